// Round 3
// baseline (1331.276 us; speedup 1.0000x reference)
//
#include <hip/hip_runtime.h>

#define L 16384

__device__ __forceinline__ float softplusf(float x){
  return (x > 20.f) ? x : log1pf(__expf(x));
}
__device__ __forceinline__ float siluf(float x){
  return x / (1.f + __expf(-x));
}
__device__ __forceinline__ float wave_sum(float v){
  #pragma unroll
  for (int o = 32; o; o >>= 1) v += __shfl_xor(v, o);
  return v;
}

// ---------------- K1: conv1 3x3 + conv2 5x5 (64->64 each), concat, relu ----
__global__ __launch_bounds__(256) void k_conv12(
    const float* __restrict__ x, const float* __restrict__ w1, const float* __restrict__ b1,
    const float* __restrict__ w2, const float* __restrict__ b2, float* __restrict__ y1)
{
  int wl = threadIdx.x;
  int ty = threadIdx.y;
  int w = blockIdx.x * 64 + wl;
  int h = blockIdx.y;
  int cz = blockIdx.z;
  if (cz < 16){
    int co = cz*4 + ty;
    float acc = b1[co];
    for (int ci = 0; ci < 64; ++ci){
      const float* wp = w1 + (co*64 + ci)*9;
      #pragma unroll
      for (int ky = 0; ky < 3; ++ky){
        int hh = h + ky - 1;
        if ((unsigned)hh < 128u){
          const float* xr = x + (ci*128 + hh)*128;
          #pragma unroll
          for (int kx = 0; kx < 3; ++kx){
            int ww = w + kx - 1;
            float xv = ((unsigned)ww < 128u) ? xr[ww] : 0.f;
            acc = fmaf(xv, wp[ky*3+kx], acc);
          }
        }
      }
    }
    y1[co*L + h*128 + w] = fmaxf(acc, 0.f);
  } else {
    int co = (cz-16)*4 + ty;
    float acc = b2[co];
    for (int ci = 0; ci < 64; ++ci){
      const float* wp = w2 + (co*64 + ci)*25;
      #pragma unroll
      for (int ky = 0; ky < 5; ++ky){
        int hh = h + ky - 2;
        if ((unsigned)hh < 128u){
          const float* xr = x + (ci*128 + hh)*128;
          #pragma unroll
          for (int kx = 0; kx < 5; ++kx){
            int ww = w + kx - 2;
            float xv = ((unsigned)ww < 128u) ? xr[ww] : 0.f;
            acc = fmaf(xv, wp[ky*5+kx], acc);
          }
        }
      }
    }
    y1[(64+co)*L + h*128 + w] = fmaxf(acc, 0.f);
  }
}

// ---------------- K2: grouped conv dw1a (128ch, groups=64, 2in/2out, 3x3) ---
__global__ __launch_bounds__(256) void k_dw1a(
    const float* __restrict__ y1, const float* __restrict__ w, const float* __restrict__ b,
    float* __restrict__ t1)
{
  int g = blockIdx.x * 256 + threadIdx.x;      // 128 * 16384 threads
  int p = g & (L-1);
  int o = g >> 14;
  int h = p >> 7, ww = p & 127;
  int grp = o >> 1;
  float acc = b[o];
  #pragma unroll
  for (int i = 0; i < 2; ++i){
    const float* xp = y1 + (grp*2 + i)*L;
    const float* wp = w + (o*2 + i)*9;
    #pragma unroll
    for (int ky = 0; ky < 3; ++ky){
      int hh = h + ky - 1;
      if ((unsigned)hh < 128u){
        #pragma unroll
        for (int kx = 0; kx < 3; ++kx){
          int wx = ww + kx - 1;
          if ((unsigned)wx < 128u)
            acc = fmaf(xp[hh*128 + wx], wp[ky*3+kx], acc);
        }
      }
    }
  }
  t1[o*L + p] = acc;
}

// ---------------- K3: 1x1 conv 128->64 + bias + relu + global sum/sumsq ----
__global__ __launch_bounds__(256) void k_dw1b(
    const float* __restrict__ t1, const float* __restrict__ w, const float* __restrict__ b,
    float* __restrict__ y2, float* __restrict__ red)
{
  __shared__ float s[16][130];
  __shared__ float rs[4][2];
  int p0 = blockIdx.x * 16;
  for (int i = threadIdx.x; i < 2048; i += 256){
    int ci = i >> 4, dp = i & 15;
    s[dp][ci] = t1[ci*L + p0 + dp];
  }
  __syncthreads();
  int dp = threadIdx.x & 15, cg = threadIdx.x >> 4;
  float lsum = 0.f, lsq = 0.f;
  #pragma unroll
  for (int cc = 0; cc < 4; ++cc){
    int c = cg + cc*16;
    float acc = b[c];
    const float* wp = w + c*128;
    #pragma unroll 8
    for (int i = 0; i < 128; ++i) acc = fmaf(s[dp][i], wp[i], acc);
    acc = fmaxf(acc, 0.f);
    y2[c*L + p0 + dp] = acc;
    lsum += acc; lsq += acc*acc;
  }
  lsum = wave_sum(lsum); lsq = wave_sum(lsq);
  if ((threadIdx.x & 63) == 0){ rs[threadIdx.x>>6][0] = lsum; rs[threadIdx.x>>6][1] = lsq; }
  __syncthreads();
  if (threadIdx.x == 0){
    float a = rs[0][0]+rs[1][0]+rs[2][0]+rs[3][0];
    float q = rs[0][1]+rs[1][1]+rs[2][1]+rs[3][1];
    atomicAdd(&red[0], a);
    atomicAdd(&red[1], q);
  }
}

// ------- K4: global norm + per-pixel LN(64) + in_proj (64->256) ------------
__global__ __launch_bounds__(256) void k_norm_inproj(
    const float* __restrict__ y2, const float* __restrict__ red,
    const float* __restrict__ ln_g, const float* __restrict__ ln_b,
    const float* __restrict__ ipw,
    float* __restrict__ ynorm, float* __restrict__ xa_pre, float* __restrict__ sz)
{
  __shared__ float ls[4][64];
  int wv = threadIdx.x >> 6, c = threadIdx.x & 63;
  int p = blockIdx.x*4 + wv;
  const float invN = 1.f / 1048576.f;
  float mu = red[0] * invN;
  float var = red[1] * invN - mu*mu;
  float rsg = rsqrtf(var + 1e-5f);
  float v = (y2[c*L + p] - mu) * rsg;
  ynorm[p*64 + c] = v;
  float s = wave_sum(v);
  float sq = wave_sum(v*v);
  float m = s * (1.f/64.f);
  float va = sq * (1.f/64.f) - m*m;
  float ln = (v - m) * rsqrtf(va + 1e-5f) * ln_g[c] + ln_b[c];
  ls[wv][c] = ln;
  __syncthreads();
  const float4* lr = (const float4*)(&ls[wv][0]);
  #pragma unroll
  for (int j = 0; j < 4; ++j){
    int e = c + 64*j;
    const float4* wr = (const float4*)(ipw + e*64);
    float acc = 0.f;
    #pragma unroll
    for (int i = 0; i < 16; ++i){
      float4 a = lr[i], bw = wr[i];
      acc = fmaf(a.x, bw.x, acc); acc = fmaf(a.y, bw.y, acc);
      acc = fmaf(a.z, bw.z, acc); acc = fmaf(a.w, bw.w, acc);
    }
    if (j < 2) xa_pre[e*L + p] = acc;
    else       sz[p*128 + (e-128)] = siluf(acc);
  }
}

// ---------------- K5: depthwise 3x3 (128ch) + bias + silu ------------------
__global__ __launch_bounds__(256) void k_dwc(
    const float* __restrict__ xa, const float* __restrict__ w, const float* __restrict__ b,
    float* __restrict__ u)
{
  int g = blockIdx.x * 256 + threadIdx.x;
  int p = g & (L-1);
  int d = g >> 14;
  int h = p >> 7, ww = p & 127;
  const float* xp = xa + d*L;
  const float* wp = w + d*9;
  float acc = b[d];
  #pragma unroll
  for (int ky = 0; ky < 3; ++ky){
    int hh = h + ky - 1;
    if ((unsigned)hh < 128u){
      #pragma unroll
      for (int kx = 0; kx < 3; ++kx){
        int wx = ww + kx - 1;
        if ((unsigned)wx < 128u)
          acc = fmaf(xp[hh*128 + wx], wp[ky*3+kx], acc);
      }
    }
  }
  u[d*L + p] = siluf(acc);
}

// ------- K6: per-pixel x_proj (128->36) + delta softplus, scan-order store -
template<int PASS>  // PASS 0: k={0,2}, row-major idx=p ; PASS 1: k={1,3}, idx = w*128+h
__global__ __launch_bounds__(256) void k_proj(
    const float* __restrict__ u, const float* __restrict__ xw,
    const float* __restrict__ dtw, const float* __restrict__ dtb,
    float* __restrict__ delta_s, float* __restrict__ Bs, float* __restrict__ Cs,
    float* __restrict__ u_out)
{
  __shared__ float us[16][132];
  __shared__ float dts[16][2][4];
  int bb = blockIdx.x;
  int tid = threadIdx.x;
  for (int i = tid; i < 16*128; i += 256){
    int d = i >> 4, pix = i & 15;
    int idx = bb*16 + pix;
    int p;
    if (PASS == 0) p = idx;
    else           p = (idx & 127)*128 + (idx >> 7);
    us[pix][d] = u[d*L + p];
  }
  __syncthreads();
  for (int o = tid; o < 1152; o += 256){
    int pix = o / 72; int r = o % 72; int kk = r / 36; int c = r % 36;
    int k = (PASS == 0) ? kk*2 : kk*2 + 1;
    const float4* ur = (const float4*)(&us[pix][0]);
    const float4* wr = (const float4*)(xw + (k*36 + c)*128);
    float acc = 0.f;
    #pragma unroll
    for (int i = 0; i < 32; ++i){
      float4 a = ur[i], bw = wr[i];
      acc = fmaf(a.x, bw.x, acc); acc = fmaf(a.y, bw.y, acc);
      acc = fmaf(a.z, bw.z, acc); acc = fmaf(a.w, bw.w, acc);
    }
    int idx = bb*16 + pix;
    if (c < 4)        dts[pix][kk][c] = acc;
    else if (c < 20)  Bs[(k*L + idx)*16 + (c-4)]  = acc;
    else              Cs[(k*L + idx)*16 + (c-20)] = acc;
  }
  __syncthreads();
  int d = tid & 127, ph = tid >> 7;
  #pragma unroll
  for (int pp = 0; pp < 8; ++pp){
    int pix = pp*2 + ph;
    int idx = bb*16 + pix;
    #pragma unroll
    for (int kk = 0; kk < 2; ++kk){
      int k = (PASS == 0) ? kk*2 : kk*2 + 1;
      const float4 dw = *((const float4*)(dtw + (k*128 + d)*4));
      float acc = dtb[k*128 + d];
      acc = fmaf(dts[pix][kk][0], dw.x, acc);
      acc = fmaf(dts[pix][kk][1], dw.y, acc);
      acc = fmaf(dts[pix][kk][2], dw.z, acc);
      acc = fmaf(dts[pix][kk][3], dw.w, acc);
      delta_s[(k*L + idx)*128 + d] = softplusf(acc);
    }
    u_out[idx*128 + d] = us[pix][d];
  }
}

// ---------------- K7: scan pass 1 — per-chunk (prod a, local h) ------------
__global__ __launch_bounds__(128) void k_scan1(
    const float* __restrict__ delta_s, const float* __restrict__ u_row,
    const float* __restrict__ u_col, const float* __restrict__ Bs,
    const float* __restrict__ Alog, float* __restrict__ P, float* __restrict__ S)
{
  int blk = blockIdx.x;          // k*64 + chunk
  int k = blk >> 6, ch = blk & 63;
  int d = threadIdx.x;
  const float* u_s = (k & 1) ? u_col : u_row;
  float A[16], Pv[16], Sv[16];
  #pragma unroll
  for (int n = 0; n < 16; ++n){
    A[n] = -__expf(Alog[(k*128 + d)*16 + n]);
    Pv[n] = 1.f; Sv[n] = 0.f;
  }
  int base = ch*256;
  for (int t = 0; t < 256; ++t){
    int tl = base + t;
    int pos = (k < 2) ? tl : (L-1 - tl);
    float dl = delta_s[(k*L + pos)*128 + d];
    float du = dl * u_s[pos*128 + d];
    const float* Br = Bs + (k*L + pos)*16;
    #pragma unroll
    for (int n = 0; n < 16; ++n){
      float a = __expf(dl * A[n]);
      Sv[n] = fmaf(Sv[n], a, du * Br[n]);
      Pv[n] *= a;
    }
  }
  #pragma unroll
  for (int n = 0; n < 16; ++n){
    int o = (blk*16 + n)*128 + d;
    P[o] = Pv[n]; S[o] = Sv[n];
  }
}

// ---------------- K8: scan pass 2 — sequential over 64 chunks --------------
__global__ __launch_bounds__(256) void k_scan2(
    const float* __restrict__ P, const float* __restrict__ S, float* __restrict__ hst)
{
  int g = blockIdx.x * 256 + threadIdx.x;   // 8192 threads: k*2048 + n*128 + d
  int d = g & 127, n = (g >> 7) & 15, k = g >> 11;
  float h = 0.f;
  for (int c = 0; c < 64; ++c){
    int o = (((k*64 + c)*16) + n)*128 + d;
    hst[o] = h;
    h = fmaf(P[o], h, S[o]);
  }
}

// ---------------- K9: scan pass 3 — outputs with corrected h_start ---------
__global__ __launch_bounds__(128) void k_scan3(
    const float* __restrict__ delta_s, const float* __restrict__ u_row,
    const float* __restrict__ u_col, const float* __restrict__ Bs,
    const float* __restrict__ Cs, const float* __restrict__ Alog,
    const float* __restrict__ hst, float* __restrict__ ys)
{
  int blk = blockIdx.x;
  int k = blk >> 6, ch = blk & 63;
  int d = threadIdx.x;
  const float* u_s = (k & 1) ? u_col : u_row;
  float A[16], h[16];
  #pragma unroll
  for (int n = 0; n < 16; ++n){
    A[n] = -__expf(Alog[(k*128 + d)*16 + n]);
    h[n] = hst[(blk*16 + n)*128 + d];
  }
  int base = ch*256;
  for (int t = 0; t < 256; ++t){
    int tl = base + t;
    int pos = (k < 2) ? tl : (L-1 - tl);
    float dl = delta_s[(k*L + pos)*128 + d];
    float du = dl * u_s[pos*128 + d];
    const float* Br = Bs + (k*L + pos)*16;
    const float* Cr = Cs + (k*L + pos)*16;
    float y = 0.f;
    #pragma unroll
    for (int n = 0; n < 16; ++n){
      float a = __expf(dl * A[n]);
      h[n] = fmaf(h[n], a, du * Br[n]);
      y = fmaf(h[n], Cr[n], y);
    }
    ys[(k*L + pos)*128 + d] = y;
  }
}

// ------- K10: combine 4 dirs + u*sumD + LN(128) + gate + out_proj + add ----
__global__ __launch_bounds__(128) void k_combine(
    const float* __restrict__ ys, const float* __restrict__ u_row,
    const float* __restrict__ Ds, const float* __restrict__ on_g,
    const float* __restrict__ on_b, const float* __restrict__ sz,
    const float* __restrict__ out_w, const float* __restrict__ ynorm,
    float* __restrict__ yp2)
{
  __shared__ float gs[128];
  __shared__ float rbuf[2][2];
  int p = blockIdx.x;
  int d = threadIdx.x;
  int h = p >> 7, w = p & 127;
  int pT = w*128 + h;
  float y = ys[(0*L + p )*128 + d] + ys[(2*L + p )*128 + d]
          + ys[(1*L + pT)*128 + d] + ys[(3*L + pT)*128 + d];
  float sumD = Ds[d] + Ds[128 + d] + Ds[256 + d] + Ds[384 + d];
  y = fmaf(u_row[p*128 + d], sumD, y);
  float s = wave_sum(y);
  float sq = wave_sum(y*y);
  if ((d & 63) == 0){ rbuf[d>>6][0] = s; rbuf[d>>6][1] = sq; }
  __syncthreads();
  float ts = rbuf[0][0] + rbuf[1][0];
  float tq = rbuf[0][1] + rbuf[1][1];
  float m = ts * (1.f/128.f);
  float va = tq * (1.f/128.f) - m*m;
  float yn = (y - m) * rsqrtf(va + 1e-5f) * on_g[d] + on_b[d];
  gs[d] = yn * sz[p*128 + d];
  __syncthreads();
  if (d < 64){
    const float4* wr = (const float4*)(out_w + d*128);
    const float4* gr = (const float4*)gs;
    float acc = 0.f;
    #pragma unroll
    for (int i = 0; i < 32; ++i){
      float4 a = gr[i], bw = wr[i];
      acc = fmaf(a.x, bw.x, acc); acc = fmaf(a.y, bw.y, acc);
      acc = fmaf(a.z, bw.z, acc); acc = fmaf(a.w, bw.w, acc);
    }
    yp2[p*64 + d] = ynorm[p*64 + d] + acc;
  }
}

// ---------------- K11: depthwise 3x3 (64ch, NHWC) + bias -------------------
__global__ __launch_bounds__(256) void k_dw2a(
    const float* __restrict__ yp2, const float* __restrict__ w,
    const float* __restrict__ b, float* __restrict__ t2)
{
  int g = blockIdx.x * 256 + threadIdx.x;   // 64 * 16384
  int c = g & 63;
  int p = g >> 6;
  int h = p >> 7, ww = p & 127;
  const float* wp = w + c*9;
  float acc = b[c];
  #pragma unroll
  for (int ky = 0; ky < 3; ++ky){
    int hh = h + ky - 1;
    if ((unsigned)hh < 128u){
      #pragma unroll
      for (int kx = 0; kx < 3; ++kx){
        int wx = ww + kx - 1;
        if ((unsigned)wx < 128u)
          acc = fmaf(yp2[(hh*128 + wx)*64 + c], wp[ky*3+kx], acc);
      }
    }
  }
  t2[p*64 + c] = acc;
}

// ---------------- K12: 1x1 64->64 + bias + relu + residual -----------------
__global__ __launch_bounds__(256) void k_dw2b(
    const float* __restrict__ t2, const float* __restrict__ w,
    const float* __restrict__ b, const float* __restrict__ x,
    float* __restrict__ out)
{
  __shared__ float s[16][65];
  int p0 = blockIdx.x * 16;
  for (int i = threadIdx.x; i < 1024; i += 256){
    int pix = i >> 6, c = i & 63;
    s[pix][c] = t2[(p0 + pix)*64 + c];
  }
  __syncthreads();
  int dp = threadIdx.x & 15, cg = threadIdx.x >> 4;
  #pragma unroll
  for (int cc = 0; cc < 4; ++cc){
    int c = cg + cc*16;
    float acc = b[c];
    const float* wp = w + c*64;
    #pragma unroll 8
    for (int i = 0; i < 64; ++i) acc = fmaf(s[dp][i], wp[i], acc);
    acc = fmaxf(acc, 0.f);
    int p = p0 + dp;
    out[c*L + p] = acc + x[c*L + p];
  }
}

extern "C" void kernel_launch(void* const* d_in, const int* in_sizes, int n_in,
                              void* d_out, int out_size, void* d_ws, size_t ws_size,
                              hipStream_t stream)
{
  const float* x       = (const float*)d_in[0];
  const float* conv1_w = (const float*)d_in[1];
  const float* conv1_b = (const float*)d_in[2];
  const float* conv2_w = (const float*)d_in[3];
  const float* conv2_b = (const float*)d_in[4];
  const float* dw1a_w  = (const float*)d_in[5];
  const float* dw1a_b  = (const float*)d_in[6];
  const float* dw1b_w  = (const float*)d_in[7];
  const float* dw1b_b  = (const float*)d_in[8];
  const float* dw2a_w  = (const float*)d_in[9];
  const float* dw2a_b  = (const float*)d_in[10];
  const float* dw2b_w  = (const float*)d_in[11];
  const float* dw2b_b  = (const float*)d_in[12];
  const float* ln_g    = (const float*)d_in[13];
  const float* ln_b    = (const float*)d_in[14];
  const float* ipw     = (const float*)d_in[15];
  const float* cdw_w   = (const float*)d_in[16];
  const float* cdw_b   = (const float*)d_in[17];
  const float* xw      = (const float*)d_in[18];
  const float* dtw     = (const float*)d_in[19];
  const float* dtb     = (const float*)d_in[20];
  const float* Alog    = (const float*)d_in[21];
  const float* DsArr   = (const float*)d_in[22];
  const float* on_g    = (const float*)d_in[23];
  const float* on_b    = (const float*)d_in[24];
  const float* out_w   = (const float*)d_in[25];
  float* out = (float*)d_out;

  char* ws = (char*)d_ws;
  const size_t MB = 1048576ull;
  float* y1      = (float*)(ws + 0*MB);    // 8MB   K1 -> K2
  float* t1      = (float*)(ws + 8*MB);    // 8MB   K2 -> K3
  float* y2      = (float*)(ws + 16*MB);   // 4MB   K3 -> K4
  float* xa_pre  = (float*)(ws + 20*MB);   // 8MB   K4 -> K5
  float* ysb     = (float*)(ws + 0*MB);    // 32MB  K9 -> K10 (reuses y1/t1/y2/xa)
  float* delta_s = (float*)(ws + 32*MB);   // 32MB  K6 -> K7/K9
  float* ynorm   = (float*)(ws + 64*MB);   // 4MB   K4 -> K10
  float* sz      = (float*)(ws + 68*MB);   // 8MB   K4 -> K10
  float* u       = (float*)(ws + 76*MB);   // 8MB   K5 -> K6
  float* u_row   = (float*)(ws + 84*MB);   // 8MB   K6 -> K7/K9/K10
  float* u_col   = (float*)(ws + 92*MB);   // 8MB   K6 -> K7/K9
  float* Bsb     = (float*)(ws + 100*MB);  // 4MB   K6 -> K7/K9
  float* Csb     = (float*)(ws + 104*MB);  // 4MB   K6 -> K9
  float* Pb      = (float*)(ws + 108*MB);  // 2MB   K7 -> K8
  float* Sb      = (float*)(ws + 110*MB);  // 2MB   K7 -> K8
  float* hst     = (float*)(ws + 112*MB);  // 2MB   K8 -> K9
  float* yp2     = (float*)(ws + 114*MB);  // 4MB   K10 -> K11
  float* t2      = (float*)(ws + 118*MB);  // 4MB   K11 -> K12
  float* red     = (float*)(ws + 122*MB);  // 8B    K3 -> K4

  hipMemsetAsync(red, 0, 2*sizeof(float), stream);

  k_conv12<<<dim3(2,128,32), dim3(64,4), 0, stream>>>(x, conv1_w, conv1_b, conv2_w, conv2_b, y1);
  k_dw1a  <<<8192, 256, 0, stream>>>(y1, dw1a_w, dw1a_b, t1);
  k_dw1b  <<<1024, 256, 0, stream>>>(t1, dw1b_w, dw1b_b, y2, red);
  k_norm_inproj<<<4096, 256, 0, stream>>>(y2, red, ln_g, ln_b, ipw, ynorm, xa_pre, sz);
  k_dwc   <<<8192, 256, 0, stream>>>(xa_pre, cdw_w, cdw_b, u);
  k_proj<0><<<1024, 256, 0, stream>>>(u, xw, dtw, dtb, delta_s, Bsb, Csb, u_row);
  k_proj<1><<<1024, 256, 0, stream>>>(u, xw, dtw, dtb, delta_s, Bsb, Csb, u_col);
  k_scan1 <<<256, 128, 0, stream>>>(delta_s, u_row, u_col, Bsb, Alog, Pb, Sb);
  k_scan2 <<<32, 256, 0, stream>>>(Pb, Sb, hst);
  k_scan3 <<<256, 128, 0, stream>>>(delta_s, u_row, u_col, Bsb, Csb, Alog, hst, ysb);
  k_combine<<<16384, 128, 0, stream>>>(ysb, u_row, DsArr, on_g, on_b, sz, out_w, ynorm, yp2);
  k_dw2a  <<<4096, 256, 0, stream>>>(yp2, dw2a_w, dw2a_b, t2);
  k_dw2b  <<<1024, 256, 0, stream>>>(t2, dw2b_w, dw2b_b, x, out);
}

// Round 4
// 998.775 us; speedup vs baseline: 1.3329x; 1.3329x over previous
//
#include <hip/hip_runtime.h>

#define L 16384

__device__ __forceinline__ float softplusf(float x){
  return (x > 20.f) ? x : log1pf(__expf(x));
}
__device__ __forceinline__ float siluf(float x){
  return x / (1.f + __expf(-x));
}
__device__ __forceinline__ float wave_sum(float v){
  #pragma unroll
  for (int o = 32; o; o >>= 1) v += __shfl_xor(v, o);
  return v;
}

// ---------------- K1: dense conv KSxKS 64->64, relu, register-blocked ------
// Block: 256 thr = 4 waves. 8x8 pixel tile; wave w owns output channels
// [16w,16w+16). Lane = pixel. acc[16] gives 16 independent FMA chains.
// LDS: x-tile (CC input ch, halo P) + weights [CC][KS*KS][64co].
template<int KS, int CC>
__global__ __launch_bounds__(256) void k_conv(
    const float* __restrict__ x, const float* __restrict__ w,
    const float* __restrict__ b, float* __restrict__ y)
{
  constexpr int P   = KS/2;
  constexpr int XS  = 8 + 2*P;     // x-tile edge
  constexpr int XST = XS + 2;      // padded stride (bank spread)
  constexpr int NT  = KS*KS;
  __shared__ float xs[CC][XS][XST];
  __shared__ float ws[CC][NT][64];
  const int tid  = threadIdx.x;
  const int lane = tid & 63;
  const int wid  = tid >> 6;
  const int px = lane & 7, py = lane >> 3;
  const int bx = blockIdx.x & 15, by = blockIdx.x >> 4;
  const int w0 = bx*8, h0 = by*8;
  const int cob = wid*16;
  float acc[16];
  #pragma unroll
  for (int i = 0; i < 16; ++i) acc[i] = b[cob+i];

  for (int cc = 0; cc < 64; cc += CC){
    __syncthreads();
    // stage x tile (zero-padded halo)
    for (int idx = tid; idx < CC*XS*XS; idx += 256){
      int ci = idx / (XS*XS); int r = idx % (XS*XS);
      int yy = r / XS, xx = r % XS;
      int gh = h0 - P + yy, gw = w0 - P + xx;
      float v = 0.f;
      if ((unsigned)gh < 128u && (unsigned)gw < 128u)
        v = x[(cc+ci)*L + gh*128 + gw];
      xs[ci][yy][xx] = v;
    }
    // stage weights: [ci][tap][co], co contiguous for float4 reads
    {
      constexpr int PER = CC*NT;            // floats per co this chunk
      int co = tid >> 2, q = tid & 3;
      const float* wg = w + co*(64*NT) + cc*NT;
      for (int j = q; j < PER; j += 4){
        int ci = j / NT, tap = j % NT;
        ws[ci][tap][co] = wg[j];
      }
    }
    __syncthreads();
    #pragma unroll 2
    for (int ci = 0; ci < CC; ++ci){
      #pragma unroll
      for (int ky = 0; ky < KS; ++ky){
        float xv[KS];
        #pragma unroll
        for (int kx = 0; kx < KS; ++kx) xv[kx] = xs[ci][py+ky][px+kx];
        #pragma unroll
        for (int kx = 0; kx < KS; ++kx){
          const int tap = ky*KS + kx;
          #pragma unroll
          for (int q = 0; q < 4; ++q){
            float4 wv = *(const float4*)&ws[ci][tap][cob + q*4];
            acc[q*4+0] = fmaf(xv[kx], wv.x, acc[q*4+0]);
            acc[q*4+1] = fmaf(xv[kx], wv.y, acc[q*4+1]);
            acc[q*4+2] = fmaf(xv[kx], wv.z, acc[q*4+2]);
            acc[q*4+3] = fmaf(xv[kx], wv.w, acc[q*4+3]);
          }
        }
      }
    }
  }
  const int p = (h0+py)*128 + (w0+px);
  #pragma unroll
  for (int i = 0; i < 16; ++i)
    y[(cob+i)*L + p] = fmaxf(acc[i], 0.f);
}

// ---------------- K2: grouped conv dw1a (128ch, groups=64, 2in/2out, 3x3) ---
__global__ __launch_bounds__(256) void k_dw1a(
    const float* __restrict__ y1, const float* __restrict__ w, const float* __restrict__ b,
    float* __restrict__ t1)
{
  int g = blockIdx.x * 256 + threadIdx.x;      // 128 * 16384 threads
  int p = g & (L-1);
  int o = g >> 14;
  int h = p >> 7, ww = p & 127;
  int grp = o >> 1;
  float acc = b[o];
  #pragma unroll
  for (int i = 0; i < 2; ++i){
    const float* xp = y1 + (grp*2 + i)*L;
    const float* wp = w + (o*2 + i)*9;
    #pragma unroll
    for (int ky = 0; ky < 3; ++ky){
      int hh = h + ky - 1;
      if ((unsigned)hh < 128u){
        #pragma unroll
        for (int kx = 0; kx < 3; ++kx){
          int wx = ww + kx - 1;
          if ((unsigned)wx < 128u)
            acc = fmaf(xp[hh*128 + wx], wp[ky*3+kx], acc);
        }
      }
    }
  }
  t1[o*L + p] = acc;
}

// ---------------- K3: 1x1 conv 128->64 + bias + relu + global sum/sumsq ----
__global__ __launch_bounds__(256) void k_dw1b(
    const float* __restrict__ t1, const float* __restrict__ w, const float* __restrict__ b,
    float* __restrict__ y2, float* __restrict__ red)
{
  __shared__ float s[16][130];
  __shared__ float rs[4][2];
  int p0 = blockIdx.x * 16;
  for (int i = threadIdx.x; i < 2048; i += 256){
    int ci = i >> 4, dp = i & 15;
    s[dp][ci] = t1[ci*L + p0 + dp];
  }
  __syncthreads();
  int dp = threadIdx.x & 15, cg = threadIdx.x >> 4;
  float lsum = 0.f, lsq = 0.f;
  #pragma unroll
  for (int cc = 0; cc < 4; ++cc){
    int c = cg + cc*16;
    float acc = b[c];
    const float* wp = w + c*128;
    #pragma unroll 8
    for (int i = 0; i < 128; ++i) acc = fmaf(s[dp][i], wp[i], acc);
    acc = fmaxf(acc, 0.f);
    y2[c*L + p0 + dp] = acc;
    lsum += acc; lsq += acc*acc;
  }
  lsum = wave_sum(lsum); lsq = wave_sum(lsq);
  if ((threadIdx.x & 63) == 0){ rs[threadIdx.x>>6][0] = lsum; rs[threadIdx.x>>6][1] = lsq; }
  __syncthreads();
  if (threadIdx.x == 0){
    float a = rs[0][0]+rs[1][0]+rs[2][0]+rs[3][0];
    float q = rs[0][1]+rs[1][1]+rs[2][1]+rs[3][1];
    atomicAdd(&red[0], a);
    atomicAdd(&red[1], q);
  }
}

// ------- K4: global norm + per-pixel LN(64) + in_proj (64->256) ------------
__global__ __launch_bounds__(256) void k_norm_inproj(
    const float* __restrict__ y2, const float* __restrict__ red,
    const float* __restrict__ ln_g, const float* __restrict__ ln_b,
    const float* __restrict__ ipw,
    float* __restrict__ ynorm, float* __restrict__ xa_pre, float* __restrict__ sz)
{
  __shared__ float ls[4][64];
  int wv = threadIdx.x >> 6, c = threadIdx.x & 63;
  int p = blockIdx.x*4 + wv;
  const float invN = 1.f / 1048576.f;
  float mu = red[0] * invN;
  float var = red[1] * invN - mu*mu;
  float rsg = rsqrtf(var + 1e-5f);
  float v = (y2[c*L + p] - mu) * rsg;
  ynorm[p*64 + c] = v;
  float s = wave_sum(v);
  float sq = wave_sum(v*v);
  float m = s * (1.f/64.f);
  float va = sq * (1.f/64.f) - m*m;
  float ln = (v - m) * rsqrtf(va + 1e-5f) * ln_g[c] + ln_b[c];
  ls[wv][c] = ln;
  __syncthreads();
  const float4* lr = (const float4*)(&ls[wv][0]);
  #pragma unroll
  for (int j = 0; j < 4; ++j){
    int e = c + 64*j;
    const float4* wr = (const float4*)(ipw + e*64);
    float acc = 0.f;
    #pragma unroll
    for (int i = 0; i < 16; ++i){
      float4 a = lr[i], bw = wr[i];
      acc = fmaf(a.x, bw.x, acc); acc = fmaf(a.y, bw.y, acc);
      acc = fmaf(a.z, bw.z, acc); acc = fmaf(a.w, bw.w, acc);
    }
    if (j < 2) xa_pre[e*L + p] = acc;
    else       sz[p*128 + (e-128)] = siluf(acc);
  }
}

// ---------------- K5: depthwise 3x3 (128ch) + bias + silu ------------------
__global__ __launch_bounds__(256) void k_dwc(
    const float* __restrict__ xa, const float* __restrict__ w, const float* __restrict__ b,
    float* __restrict__ u)
{
  int g = blockIdx.x * 256 + threadIdx.x;
  int p = g & (L-1);
  int d = g >> 14;
  int h = p >> 7, ww = p & 127;
  const float* xp = xa + d*L;
  const float* wp = w + d*9;
  float acc = b[d];
  #pragma unroll
  for (int ky = 0; ky < 3; ++ky){
    int hh = h + ky - 1;
    if ((unsigned)hh < 128u){
      #pragma unroll
      for (int kx = 0; kx < 3; ++kx){
        int wx = ww + kx - 1;
        if ((unsigned)wx < 128u)
          acc = fmaf(xp[hh*128 + wx], wp[ky*3+kx], acc);
      }
    }
  }
  u[d*L + p] = siluf(acc);
}

// ------- K6: per-pixel x_proj (128->36) + delta softplus, scan-order store -
template<int PASS>  // PASS 0: k={0,2}, row-major idx=p ; PASS 1: k={1,3}, idx = w*128+h
__global__ __launch_bounds__(256) void k_proj(
    const float* __restrict__ u, const float* __restrict__ xw,
    const float* __restrict__ dtw, const float* __restrict__ dtb,
    float* __restrict__ delta_s, float* __restrict__ Bs, float* __restrict__ Cs,
    float* __restrict__ u_out)
{
  __shared__ float us[16][132];
  __shared__ float dts[16][2][4];
  int bb = blockIdx.x;
  int tid = threadIdx.x;
  for (int i = tid; i < 16*128; i += 256){
    int d = i >> 4, pix = i & 15;
    int idx = bb*16 + pix;
    int p;
    if (PASS == 0) p = idx;
    else           p = (idx & 127)*128 + (idx >> 7);
    us[pix][d] = u[d*L + p];
  }
  __syncthreads();
  for (int o = tid; o < 1152; o += 256){
    int pix = o / 72; int r = o % 72; int kk = r / 36; int c = r % 36;
    int k = (PASS == 0) ? kk*2 : kk*2 + 1;
    const float4* ur = (const float4*)(&us[pix][0]);
    const float4* wr = (const float4*)(xw + (k*36 + c)*128);
    float acc = 0.f;
    #pragma unroll
    for (int i = 0; i < 32; ++i){
      float4 a = ur[i], bw = wr[i];
      acc = fmaf(a.x, bw.x, acc); acc = fmaf(a.y, bw.y, acc);
      acc = fmaf(a.z, bw.z, acc); acc = fmaf(a.w, bw.w, acc);
    }
    int idx = bb*16 + pix;
    if (c < 4)        dts[pix][kk][c] = acc;
    else if (c < 20)  Bs[(k*L + idx)*16 + (c-4)]  = acc;
    else              Cs[(k*L + idx)*16 + (c-20)] = acc;
  }
  __syncthreads();
  int d = tid & 127, ph = tid >> 7;
  #pragma unroll
  for (int pp = 0; pp < 8; ++pp){
    int pix = pp*2 + ph;
    int idx = bb*16 + pix;
    #pragma unroll
    for (int kk = 0; kk < 2; ++kk){
      int k = (PASS == 0) ? kk*2 : kk*2 + 1;
      const float4 dw = *((const float4*)(dtw + (k*128 + d)*4));
      float acc = dtb[k*128 + d];
      acc = fmaf(dts[pix][kk][0], dw.x, acc);
      acc = fmaf(dts[pix][kk][1], dw.y, acc);
      acc = fmaf(dts[pix][kk][2], dw.z, acc);
      acc = fmaf(dts[pix][kk][3], dw.w, acc);
      delta_s[(k*L + idx)*128 + d] = softplusf(acc);
    }
    u_out[idx*128 + d] = us[pix][d];
  }
}

// ---------------- K7: scan pass 1 — per-chunk (prod a, local h) ------------
__global__ __launch_bounds__(128) void k_scan1(
    const float* __restrict__ delta_s, const float* __restrict__ u_row,
    const float* __restrict__ u_col, const float* __restrict__ Bs,
    const float* __restrict__ Alog, float* __restrict__ P, float* __restrict__ S)
{
  int blk = blockIdx.x;          // k*64 + chunk
  int k = blk >> 6, ch = blk & 63;
  int d = threadIdx.x;
  const float* u_s = (k & 1) ? u_col : u_row;
  float A[16], Pv[16], Sv[16];
  #pragma unroll
  for (int n = 0; n < 16; ++n){
    A[n] = -__expf(Alog[(k*128 + d)*16 + n]);
    Pv[n] = 1.f; Sv[n] = 0.f;
  }
  int base = ch*256;
  for (int t = 0; t < 256; ++t){
    int tl = base + t;
    int pos = (k < 2) ? tl : (L-1 - tl);
    float dl = delta_s[(k*L + pos)*128 + d];
    float du = dl * u_s[pos*128 + d];
    const float* Br = Bs + (k*L + pos)*16;
    #pragma unroll
    for (int n = 0; n < 16; ++n){
      float a = __expf(dl * A[n]);
      Sv[n] = fmaf(Sv[n], a, du * Br[n]);
      Pv[n] *= a;
    }
  }
  #pragma unroll
  for (int n = 0; n < 16; ++n){
    int o = (blk*16 + n)*128 + d;
    P[o] = Pv[n]; S[o] = Sv[n];
  }
}

// ---------------- K8: scan pass 2 — sequential over 64 chunks --------------
__global__ __launch_bounds__(256) void k_scan2(
    const float* __restrict__ P, const float* __restrict__ S, float* __restrict__ hst)
{
  int g = blockIdx.x * 256 + threadIdx.x;   // 8192 threads: k*2048 + n*128 + d
  int d = g & 127, n = (g >> 7) & 15, k = g >> 11;
  float h = 0.f;
  for (int c = 0; c < 64; ++c){
    int o = (((k*64 + c)*16) + n)*128 + d;
    hst[o] = h;
    h = fmaf(P[o], h, S[o]);
  }
}

// ---------------- K9: scan pass 3 — outputs with corrected h_start ---------
__global__ __launch_bounds__(128) void k_scan3(
    const float* __restrict__ delta_s, const float* __restrict__ u_row,
    const float* __restrict__ u_col, const float* __restrict__ Bs,
    const float* __restrict__ Cs, const float* __restrict__ Alog,
    const float* __restrict__ hst, float* __restrict__ ys)
{
  int blk = blockIdx.x;
  int k = blk >> 6, ch = blk & 63;
  int d = threadIdx.x;
  const float* u_s = (k & 1) ? u_col : u_row;
  float A[16], h[16];
  #pragma unroll
  for (int n = 0; n < 16; ++n){
    A[n] = -__expf(Alog[(k*128 + d)*16 + n]);
    h[n] = hst[(blk*16 + n)*128 + d];
  }
  int base = ch*256;
  for (int t = 0; t < 256; ++t){
    int tl = base + t;
    int pos = (k < 2) ? tl : (L-1 - tl);
    float dl = delta_s[(k*L + pos)*128 + d];
    float du = dl * u_s[pos*128 + d];
    const float* Br = Bs + (k*L + pos)*16;
    const float* Cr = Cs + (k*L + pos)*16;
    float y = 0.f;
    #pragma unroll
    for (int n = 0; n < 16; ++n){
      float a = __expf(dl * A[n]);
      h[n] = fmaf(h[n], a, du * Br[n]);
      y = fmaf(h[n], Cr[n], y);
    }
    ys[(k*L + pos)*128 + d] = y;
  }
}

// ------- K10: combine 4 dirs + u*sumD + LN(128) + gate + out_proj + add ----
__global__ __launch_bounds__(128) void k_combine(
    const float* __restrict__ ys, const float* __restrict__ u_row,
    const float* __restrict__ Ds, const float* __restrict__ on_g,
    const float* __restrict__ on_b, const float* __restrict__ sz,
    const float* __restrict__ out_w, const float* __restrict__ ynorm,
    float* __restrict__ yp2)
{
  __shared__ float gs[128];
  __shared__ float rbuf[2][2];
  int p = blockIdx.x;
  int d = threadIdx.x;
  int h = p >> 7, w = p & 127;
  int pT = w*128 + h;
  float y = ys[(0*L + p )*128 + d] + ys[(2*L + p )*128 + d]
          + ys[(1*L + pT)*128 + d] + ys[(3*L + pT)*128 + d];
  float sumD = Ds[d] + Ds[128 + d] + Ds[256 + d] + Ds[384 + d];
  y = fmaf(u_row[p*128 + d], sumD, y);
  float s = wave_sum(y);
  float sq = wave_sum(y*y);
  if ((d & 63) == 0){ rbuf[d>>6][0] = s; rbuf[d>>6][1] = sq; }
  __syncthreads();
  float ts = rbuf[0][0] + rbuf[1][0];
  float tq = rbuf[0][1] + rbuf[1][1];
  float m = ts * (1.f/128.f);
  float va = tq * (1.f/128.f) - m*m;
  float yn = (y - m) * rsqrtf(va + 1e-5f) * on_g[d] + on_b[d];
  gs[d] = yn * sz[p*128 + d];
  __syncthreads();
  if (d < 64){
    const float4* wr = (const float4*)(out_w + d*128);
    const float4* gr = (const float4*)gs;
    float acc = 0.f;
    #pragma unroll
    for (int i = 0; i < 32; ++i){
      float4 a = gr[i], bw = wr[i];
      acc = fmaf(a.x, bw.x, acc); acc = fmaf(a.y, bw.y, acc);
      acc = fmaf(a.z, bw.z, acc); acc = fmaf(a.w, bw.w, acc);
    }
    yp2[p*64 + d] = ynorm[p*64 + d] + acc;
  }
}

// ---------------- K11: depthwise 3x3 (64ch, NHWC) + bias -------------------
__global__ __launch_bounds__(256) void k_dw2a(
    const float* __restrict__ yp2, const float* __restrict__ w,
    const float* __restrict__ b, float* __restrict__ t2)
{
  int g = blockIdx.x * 256 + threadIdx.x;   // 64 * 16384
  int c = g & 63;
  int p = g >> 6;
  int h = p >> 7, ww = p & 127;
  const float* wp = w + c*9;
  float acc = b[c];
  #pragma unroll
  for (int ky = 0; ky < 3; ++ky){
    int hh = h + ky - 1;
    if ((unsigned)hh < 128u){
      #pragma unroll
      for (int kx = 0; kx < 3; ++kx){
        int wx = ww + kx - 1;
        if ((unsigned)wx < 128u)
          acc = fmaf(yp2[(hh*128 + wx)*64 + c], wp[ky*3+kx], acc);
      }
    }
  }
  t2[p*64 + c] = acc;
}

// ---------------- K12: 1x1 64->64 + bias + relu + residual -----------------
__global__ __launch_bounds__(256) void k_dw2b(
    const float* __restrict__ t2, const float* __restrict__ w,
    const float* __restrict__ b, const float* __restrict__ x,
    float* __restrict__ out)
{
  __shared__ float s[16][65];
  int p0 = blockIdx.x * 16;
  for (int i = threadIdx.x; i < 1024; i += 256){
    int pix = i >> 6, c = i & 63;
    s[pix][c] = t2[(p0 + pix)*64 + c];
  }
  __syncthreads();
  int dp = threadIdx.x & 15, cg = threadIdx.x >> 4;
  #pragma unroll
  for (int cc = 0; cc < 4; ++cc){
    int c = cg + cc*16;
    float acc = b[c];
    const float* wp = w + c*64;
    #pragma unroll 8
    for (int i = 0; i < 64; ++i) acc = fmaf(s[dp][i], wp[i], acc);
    acc = fmaxf(acc, 0.f);
    int p = p0 + dp;
    out[c*L + p] = acc + x[c*L + p];
  }
}

extern "C" void kernel_launch(void* const* d_in, const int* in_sizes, int n_in,
                              void* d_out, int out_size, void* d_ws, size_t ws_size,
                              hipStream_t stream)
{
  const float* x       = (const float*)d_in[0];
  const float* conv1_w = (const float*)d_in[1];
  const float* conv1_b = (const float*)d_in[2];
  const float* conv2_w = (const float*)d_in[3];
  const float* conv2_b = (const float*)d_in[4];
  const float* dw1a_w  = (const float*)d_in[5];
  const float* dw1a_b  = (const float*)d_in[6];
  const float* dw1b_w  = (const float*)d_in[7];
  const float* dw1b_b  = (const float*)d_in[8];
  const float* dw2a_w  = (const float*)d_in[9];
  const float* dw2a_b  = (const float*)d_in[10];
  const float* dw2b_w  = (const float*)d_in[11];
  const float* dw2b_b  = (const float*)d_in[12];
  const float* ln_g    = (const float*)d_in[13];
  const float* ln_b    = (const float*)d_in[14];
  const float* ipw     = (const float*)d_in[15];
  const float* cdw_w   = (const float*)d_in[16];
  const float* cdw_b   = (const float*)d_in[17];
  const float* xw      = (const float*)d_in[18];
  const float* dtw     = (const float*)d_in[19];
  const float* dtb     = (const float*)d_in[20];
  const float* Alog    = (const float*)d_in[21];
  const float* DsArr   = (const float*)d_in[22];
  const float* on_g    = (const float*)d_in[23];
  const float* on_b    = (const float*)d_in[24];
  const float* out_w   = (const float*)d_in[25];
  float* out = (float*)d_out;

  char* ws = (char*)d_ws;
  const size_t MB = 1048576ull;
  float* y1      = (float*)(ws + 0*MB);    // 8MB   K1 -> K2
  float* t1      = (float*)(ws + 8*MB);    // 8MB   K2 -> K3
  float* y2      = (float*)(ws + 16*MB);   // 4MB   K3 -> K4
  float* xa_pre  = (float*)(ws + 20*MB);   // 8MB   K4 -> K5
  float* ysb     = (float*)(ws + 0*MB);    // 32MB  K9 -> K10 (reuses y1/t1/y2/xa)
  float* delta_s = (float*)(ws + 32*MB);   // 32MB  K6 -> K7/K9
  float* ynorm   = (float*)(ws + 64*MB);   // 4MB   K4 -> K10
  float* sz      = (float*)(ws + 68*MB);   // 8MB   K4 -> K10
  float* u       = (float*)(ws + 76*MB);   // 8MB   K5 -> K6
  float* u_row   = (float*)(ws + 84*MB);   // 8MB   K6 -> K7/K9/K10
  float* u_col   = (float*)(ws + 92*MB);   // 8MB   K6 -> K7/K9
  float* Bsb     = (float*)(ws + 100*MB);  // 4MB   K6 -> K7/K9
  float* Csb     = (float*)(ws + 104*MB);  // 4MB   K6 -> K9
  float* Pb      = (float*)(ws + 108*MB);  // 2MB   K7 -> K8
  float* Sb      = (float*)(ws + 110*MB);  // 2MB   K7 -> K8
  float* hst     = (float*)(ws + 112*MB);  // 2MB   K8 -> K9
  float* yp2     = (float*)(ws + 114*MB);  // 4MB   K10 -> K11
  float* t2      = (float*)(ws + 118*MB);  // 4MB   K11 -> K12
  float* red     = (float*)(ws + 122*MB);  // 8B    K3 -> K4

  hipMemsetAsync(red, 0, 2*sizeof(float), stream);

  k_conv<3,8><<<256, 256, 0, stream>>>(x, conv1_w, conv1_b, y1);
  k_conv<5,4><<<256, 256, 0, stream>>>(x, conv2_w, conv2_b, y1 + 64*L);
  k_dw1a  <<<8192, 256, 0, stream>>>(y1, dw1a_w, dw1a_b, t1);
  k_dw1b  <<<1024, 256, 0, stream>>>(t1, dw1b_w, dw1b_b, y2, red);
  k_norm_inproj<<<4096, 256, 0, stream>>>(y2, red, ln_g, ln_b, ipw, ynorm, xa_pre, sz);
  k_dwc   <<<8192, 256, 0, stream>>>(xa_pre, cdw_w, cdw_b, u);
  k_proj<0><<<1024, 256, 0, stream>>>(u, xw, dtw, dtb, delta_s, Bsb, Csb, u_row);
  k_proj<1><<<1024, 256, 0, stream>>>(u, xw, dtw, dtb, delta_s, Bsb, Csb, u_col);
  k_scan1 <<<256, 128, 0, stream>>>(delta_s, u_row, u_col, Bsb, Alog, Pb, Sb);
  k_scan2 <<<32, 256, 0, stream>>>(Pb, Sb, hst);
  k_scan3 <<<256, 128, 0, stream>>>(delta_s, u_row, u_col, Bsb, Csb, Alog, hst, ysb);
  k_combine<<<16384, 128, 0, stream>>>(ysb, u_row, DsArr, on_g, on_b, sz, out_w, ynorm, yp2);
  k_dw2a  <<<4096, 256, 0, stream>>>(yp2, dw2a_w, dw2a_b, t2);
  k_dw2b  <<<1024, 256, 0, stream>>>(t2, dw2b_w, dw2b_b, x, out);
}

// Round 5
// 919.941 us; speedup vs baseline: 1.4471x; 1.0857x over previous
//
#include <hip/hip_runtime.h>

#define L 16384

__device__ __forceinline__ float softplusf(float x){
  return (x > 20.f) ? x : log1pf(__expf(x));
}
__device__ __forceinline__ float siluf(float x){
  return x / (1.f + __expf(-x));
}
__device__ __forceinline__ float wave_sum(float v){
  #pragma unroll
  for (int o = 32; o; o >>= 1) v += __shfl_xor(v, o);
  return v;
}

// ---------------- K0: prep — transpose weights for coalesced per-lane reads
// wT1[ci*9+tap][co]  (36864)   wT2[ci*25+tap][co] (102400)   ipwT[c][e] (16384)
__global__ __launch_bounds__(256) void k_prep(
    const float* __restrict__ w1, const float* __restrict__ w2,
    const float* __restrict__ ipw,
    float* __restrict__ wT1, float* __restrict__ wT2, float* __restrict__ ipwT)
{
  int g = blockIdx.x * 256 + threadIdx.x;
  if (g < 36864){
    int co = g & 63, r = g >> 6;
    wT1[g] = w1[co*576 + r];
  } else if (g < 36864 + 102400){
    int g2 = g - 36864;
    int co = g2 & 63, r = g2 >> 6;
    wT2[g2] = w2[co*1600 + r];
  } else if (g < 36864 + 102400 + 16384){
    int g3 = g - 139264;
    int e = g3 & 255, c = g3 >> 8;
    ipwT[g3] = ipw[e*64 + c];
  }
}

// ---------------- K1: dense conv 64->64, relu. lane=co, wave=8-pixel row ---
// x window is wave-uniform -> scalar loads; weights coalesced from wT.
// Grid 512 = 16 w-tiles x 32 h-tiles; block = 4 waves = 4 rows. No LDS.
template<int KS>
__global__ __launch_bounds__(256) void k_convA(
    const float* __restrict__ x, const float* __restrict__ wT,
    const float* __restrict__ b, float* __restrict__ y)
{
  constexpr int P  = KS/2;
  constexpr int NT = KS*KS;
  constexpr int XW = 8 + 2*P;
  const int tid = threadIdx.x;
  const int co  = tid & 63;
  const int wid = __builtin_amdgcn_readfirstlane(tid >> 6);
  const int bx = blockIdx.x & 15;
  const int by = blockIdx.x >> 4;
  const int w0 = bx*8;
  const int h  = by*4 + wid;
  float acc[8];
  float bv = b[co];
  #pragma unroll
  for (int p = 0; p < 8; ++p) acc[p] = bv;

  for (int ci = 0; ci < 64; ++ci){
    const float* xp = x + ci*L;
    #pragma unroll
    for (int ky = 0; ky < KS; ++ky){
      int hh = h + ky - P;
      if ((unsigned)hh < 128u){
        const float* xr = xp + hh*128;
        float xrow[XW];
        #pragma unroll
        for (int j = 0; j < XW; ++j){
          int gw = w0 - P + j;
          int cgw = gw < 0 ? 0 : (gw > 127 ? 127 : gw);
          float v = xr[cgw];
          xrow[j] = ((unsigned)gw < 128u) ? v : 0.f;
        }
        const float* wrow = wT + (ci*NT + ky*KS)*64 + co;
        #pragma unroll
        for (int kx = 0; kx < KS; ++kx){
          float wv = wrow[kx*64];
          #pragma unroll
          for (int p = 0; p < 8; ++p)
            acc[p] = fmaf(xrow[p+kx], wv, acc[p]);
        }
      }
    }
  }
  const int pb = h*128 + w0;
  #pragma unroll
  for (int p = 0; p < 8; ++p)
    y[co*L + pb + p] = fmaxf(acc[p], 0.f);
}

// ---------------- K2: grouped conv dw1a (128ch, groups=64, 2in/2out, 3x3) ---
__global__ __launch_bounds__(256) void k_dw1a(
    const float* __restrict__ y1, const float* __restrict__ w, const float* __restrict__ b,
    float* __restrict__ t1)
{
  int g = blockIdx.x * 256 + threadIdx.x;      // 128 * 16384 threads
  int p = g & (L-1);
  int o = g >> 14;
  int h = p >> 7, ww = p & 127;
  int grp = o >> 1;
  float acc = b[o];
  #pragma unroll
  for (int i = 0; i < 2; ++i){
    const float* xp = y1 + (grp*2 + i)*L;
    const float* wp = w + (o*2 + i)*9;
    #pragma unroll
    for (int ky = 0; ky < 3; ++ky){
      int hh = h + ky - 1;
      if ((unsigned)hh < 128u){
        #pragma unroll
        for (int kx = 0; kx < 3; ++kx){
          int wx = ww + kx - 1;
          if ((unsigned)wx < 128u)
            acc = fmaf(xp[hh*128 + wx], wp[ky*3+kx], acc);
        }
      }
    }
  }
  t1[o*L + p] = acc;
}

// ---------------- K3: 1x1 conv 128->64 + bias + relu + global sum/sumsq ----
__global__ __launch_bounds__(256) void k_dw1b(
    const float* __restrict__ t1, const float* __restrict__ w, const float* __restrict__ b,
    float* __restrict__ y2, float* __restrict__ red)
{
  __shared__ float s[16][130];
  __shared__ float rs[4][2];
  int p0 = blockIdx.x * 16;
  for (int i = threadIdx.x; i < 2048; i += 256){
    int ci = i >> 4, dp = i & 15;
    s[dp][ci] = t1[ci*L + p0 + dp];
  }
  __syncthreads();
  int dp = threadIdx.x & 15, cg = threadIdx.x >> 4;
  float lsum = 0.f, lsq = 0.f;
  #pragma unroll
  for (int cc = 0; cc < 4; ++cc){
    int c = cg + cc*16;
    float acc = b[c];
    const float* wp = w + c*128;
    #pragma unroll 8
    for (int i = 0; i < 128; ++i) acc = fmaf(s[dp][i], wp[i], acc);
    acc = fmaxf(acc, 0.f);
    y2[c*L + p0 + dp] = acc;
    lsum += acc; lsq += acc*acc;
  }
  lsum = wave_sum(lsum); lsq = wave_sum(lsq);
  if ((threadIdx.x & 63) == 0){ rs[threadIdx.x>>6][0] = lsum; rs[threadIdx.x>>6][1] = lsq; }
  __syncthreads();
  if (threadIdx.x == 0){
    float a = rs[0][0]+rs[1][0]+rs[2][0]+rs[3][0];
    float q = rs[0][1]+rs[1][1]+rs[2][1]+rs[3][1];
    atomicAdd(&red[0], a);
    atomicAdd(&red[1], q);
  }
}

// ------- K4: global norm + LN(64) + in_proj (64->256), LDS-staged weights --
// Block: 256 thr, 32 pixels. ws_s = ipwT staged (64KB). thread=(pix, 32-e slice).
__global__ __launch_bounds__(256) void k_norm_inproj(
    const float* __restrict__ y2, const float* __restrict__ red,
    const float* __restrict__ ln_g, const float* __restrict__ ln_b,
    const float* __restrict__ ipwT,
    float* __restrict__ ynorm, float* __restrict__ xa_pre, float* __restrict__ sz)
{
  __shared__ float ws_s[16384];     // [c][e] 64x256
  __shared__ float ls_s[64*33];     // [c][pix] stride 33
  __shared__ float mv_s[2][32];
  const int tid = threadIdx.x;
  const int p0 = blockIdx.x * 32;
  // stage weights (overlaps with LN phases until first consumer sync)
  {
    const float4* src = (const float4*)ipwT;
    float4* dst = (float4*)ws_s;
    #pragma unroll
    for (int i = 0; i < 16; ++i) dst[tid + i*256] = src[tid + i*256];
  }
  const float invN = 1.f / 1048576.f;
  float mu = red[0] * invN;
  float var = red[1] * invN - mu*mu;
  float rsg = rsqrtf(var + 1e-5f);
  // phase 1: global-norm into ls
  for (int i = tid; i < 2048; i += 256){
    int c = i >> 5, pix = i & 31;
    ls_s[c*33 + pix] = (y2[c*L + p0 + pix] - mu) * rsg;
  }
  __syncthreads();
  // phase 1b: ynorm out (coalesced), phase 2: per-pixel mean/var
  for (int i = tid; i < 2048; i += 256){
    int pix = i >> 6, c = i & 63;
    ynorm[(p0 + pix)*64 + c] = ls_s[c*33 + pix];
  }
  if (tid < 32){
    float s = 0.f, q = 0.f;
    #pragma unroll 8
    for (int c = 0; c < 64; ++c){
      float v = ls_s[c*33 + tid];
      s += v; q += v*v;
    }
    float m = s * (1.f/64.f);
    float va = q * (1.f/64.f) - m*m;
    mv_s[0][tid] = m;
    mv_s[1][tid] = rsqrtf(va + 1e-5f);
  }
  __syncthreads();
  // phase 3: LN transform in place
  for (int i = tid; i < 2048; i += 256){
    int c = i >> 5, pix = i & 31;
    float v = ls_s[c*33 + pix];
    ls_s[c*33 + pix] = (v - mv_s[0][pix]) * mv_s[1][pix] * ln_g[c] + ln_b[c];
  }
  __syncthreads();
  // GEMM: acc over 32 e for (pix, eh)
  const int pix = tid & 31, eh = tid >> 5;
  float acc[32];
  #pragma unroll
  for (int j = 0; j < 32; ++j) acc[j] = 0.f;
  for (int c = 0; c < 64; ++c){
    float lnv = ls_s[c*33 + pix];
    const float4* w4 = (const float4*)(ws_s + c*256 + eh*32);
    #pragma unroll
    for (int j = 0; j < 8; ++j){
      float4 wq = w4[j];
      acc[j*4+0] = fmaf(lnv, wq.x, acc[j*4+0]);
      acc[j*4+1] = fmaf(lnv, wq.y, acc[j*4+1]);
      acc[j*4+2] = fmaf(lnv, wq.z, acc[j*4+2]);
      acc[j*4+3] = fmaf(lnv, wq.w, acc[j*4+3]);
    }
  }
  __syncthreads();   // ws_s reads done; safe to alias
  float* szs = ws_s; // [pix][129]
  const int p = p0 + pix;
  if (eh < 4){
    const int e0 = eh*32;
    #pragma unroll
    for (int j = 0; j < 32; ++j)
      xa_pre[(e0+j)*L + p] = acc[j];
  } else {
    const int j0 = (eh-4)*32;
    #pragma unroll
    for (int j = 0; j < 32; ++j)
      szs[pix*129 + j0 + j] = siluf(acc[j]);
  }
  __syncthreads();
  for (int i = tid; i < 32*128; i += 256){
    int pix2 = i >> 7, j = i & 127;
    sz[(p0 + pix2)*128 + j] = szs[pix2*129 + j];
  }
}

// ---------------- K5: depthwise 3x3 (128ch) + bias + silu ------------------
__global__ __launch_bounds__(256) void k_dwc(
    const float* __restrict__ xa, const float* __restrict__ w, const float* __restrict__ b,
    float* __restrict__ u)
{
  int g = blockIdx.x * 256 + threadIdx.x;
  int p = g & (L-1);
  int d = g >> 14;
  int h = p >> 7, ww = p & 127;
  const float* xp = xa + d*L;
  const float* wp = w + d*9;
  float acc = b[d];
  #pragma unroll
  for (int ky = 0; ky < 3; ++ky){
    int hh = h + ky - 1;
    if ((unsigned)hh < 128u){
      #pragma unroll
      for (int kx = 0; kx < 3; ++kx){
        int wx = ww + kx - 1;
        if ((unsigned)wx < 128u)
          acc = fmaf(xp[hh*128 + wx], wp[ky*3+kx], acc);
      }
    }
  }
  u[d*L + p] = siluf(acc);
}

// ------- K6: per-pixel x_proj (128->36) + delta softplus, scan-order store -
template<int PASS>  // PASS 0: k={0,2}, row-major idx=p ; PASS 1: k={1,3}, idx = w*128+h
__global__ __launch_bounds__(256) void k_proj(
    const float* __restrict__ u, const float* __restrict__ xw,
    const float* __restrict__ dtw, const float* __restrict__ dtb,
    float* __restrict__ delta_s, float* __restrict__ Bs, float* __restrict__ Cs,
    float* __restrict__ u_out)
{
  __shared__ float us[16][132];
  __shared__ float dts[16][2][4];
  int bb = blockIdx.x;
  int tid = threadIdx.x;
  for (int i = tid; i < 16*128; i += 256){
    int d = i >> 4, pix = i & 15;
    int idx = bb*16 + pix;
    int p;
    if (PASS == 0) p = idx;
    else           p = (idx & 127)*128 + (idx >> 7);
    us[pix][d] = u[d*L + p];
  }
  __syncthreads();
  for (int o = tid; o < 1152; o += 256){
    int pix = o / 72; int r = o % 72; int kk = r / 36; int c = r % 36;
    int k = (PASS == 0) ? kk*2 : kk*2 + 1;
    const float4* ur = (const float4*)(&us[pix][0]);
    const float4* wr = (const float4*)(xw + (k*36 + c)*128);
    float acc = 0.f;
    #pragma unroll
    for (int i = 0; i < 32; ++i){
      float4 a = ur[i], bw = wr[i];
      acc = fmaf(a.x, bw.x, acc); acc = fmaf(a.y, bw.y, acc);
      acc = fmaf(a.z, bw.z, acc); acc = fmaf(a.w, bw.w, acc);
    }
    int idx = bb*16 + pix;
    if (c < 4)        dts[pix][kk][c] = acc;
    else if (c < 20)  Bs[(k*L + idx)*16 + (c-4)]  = acc;
    else              Cs[(k*L + idx)*16 + (c-20)] = acc;
  }
  __syncthreads();
  int d = tid & 127, ph = tid >> 7;
  #pragma unroll
  for (int pp = 0; pp < 8; ++pp){
    int pix = pp*2 + ph;
    int idx = bb*16 + pix;
    #pragma unroll
    for (int kk = 0; kk < 2; ++kk){
      int k = (PASS == 0) ? kk*2 : kk*2 + 1;
      const float4 dw = *((const float4*)(dtw + (k*128 + d)*4));
      float acc = dtb[k*128 + d];
      acc = fmaf(dts[pix][kk][0], dw.x, acc);
      acc = fmaf(dts[pix][kk][1], dw.y, acc);
      acc = fmaf(dts[pix][kk][2], dw.z, acc);
      acc = fmaf(dts[pix][kk][3], dw.w, acc);
      delta_s[(k*L + idx)*128 + d] = softplusf(acc);
    }
    u_out[idx*128 + d] = us[pix][d];
  }
}

// ---------------- K7: scan pass 1 — per-chunk (prod a, local h) ------------
__global__ __launch_bounds__(128) void k_scan1(
    const float* __restrict__ delta_s, const float* __restrict__ u_row,
    const float* __restrict__ u_col, const float* __restrict__ Bs,
    const float* __restrict__ Alog, float* __restrict__ P, float* __restrict__ S)
{
  int blk = blockIdx.x;          // k*64 + chunk
  int k = blk >> 6, ch = blk & 63;
  int d = threadIdx.x;
  const float* u_s = (k & 1) ? u_col : u_row;
  float A[16], Pv[16], Sv[16];
  #pragma unroll
  for (int n = 0; n < 16; ++n){
    A[n] = -__expf(Alog[(k*128 + d)*16 + n]);
    Pv[n] = 1.f; Sv[n] = 0.f;
  }
  int base = ch*256;
  for (int t = 0; t < 256; ++t){
    int tl = base + t;
    int pos = (k < 2) ? tl : (L-1 - tl);
    float dl = delta_s[(k*L + pos)*128 + d];
    float du = dl * u_s[pos*128 + d];
    const float* Br = Bs + (k*L + pos)*16;
    #pragma unroll
    for (int n = 0; n < 16; ++n){
      float a = __expf(dl * A[n]);
      Sv[n] = fmaf(Sv[n], a, du * Br[n]);
      Pv[n] *= a;
    }
  }
  #pragma unroll
  for (int n = 0; n < 16; ++n){
    int o = (blk*16 + n)*128 + d;
    P[o] = Pv[n]; S[o] = Sv[n];
  }
}

// ---------------- K8: scan pass 2 — sequential over 64 chunks --------------
__global__ __launch_bounds__(256) void k_scan2(
    const float* __restrict__ P, const float* __restrict__ S, float* __restrict__ hst)
{
  int g = blockIdx.x * 256 + threadIdx.x;   // 8192 threads: k*2048 + n*128 + d
  int d = g & 127, n = (g >> 7) & 15, k = g >> 11;
  float h = 0.f;
  for (int c = 0; c < 64; ++c){
    int o = (((k*64 + c)*16) + n)*128 + d;
    hst[o] = h;
    h = fmaf(P[o], h, S[o]);
  }
}

// ---------------- K9: scan pass 3 — outputs with corrected h_start ---------
__global__ __launch_bounds__(128) void k_scan3(
    const float* __restrict__ delta_s, const float* __restrict__ u_row,
    const float* __restrict__ u_col, const float* __restrict__ Bs,
    const float* __restrict__ Cs, const float* __restrict__ Alog,
    const float* __restrict__ hst, float* __restrict__ ys)
{
  int blk = blockIdx.x;
  int k = blk >> 6, ch = blk & 63;
  int d = threadIdx.x;
  const float* u_s = (k & 1) ? u_col : u_row;
  float A[16], h[16];
  #pragma unroll
  for (int n = 0; n < 16; ++n){
    A[n] = -__expf(Alog[(k*128 + d)*16 + n]);
    h[n] = hst[(blk*16 + n)*128 + d];
  }
  int base = ch*256;
  for (int t = 0; t < 256; ++t){
    int tl = base + t;
    int pos = (k < 2) ? tl : (L-1 - tl);
    float dl = delta_s[(k*L + pos)*128 + d];
    float du = dl * u_s[pos*128 + d];
    const float* Br = Bs + (k*L + pos)*16;
    const float* Cr = Cs + (k*L + pos)*16;
    float y = 0.f;
    #pragma unroll
    for (int n = 0; n < 16; ++n){
      float a = __expf(dl * A[n]);
      h[n] = fmaf(h[n], a, du * Br[n]);
      y = fmaf(h[n], Cr[n], y);
    }
    ys[(k*L + pos)*128 + d] = y;
  }
}

// ------- K10: combine 4 dirs + u*sumD + LN(128) + gate + out_proj + add ----
__global__ __launch_bounds__(128) void k_combine(
    const float* __restrict__ ys, const float* __restrict__ u_row,
    const float* __restrict__ Ds, const float* __restrict__ on_g,
    const float* __restrict__ on_b, const float* __restrict__ sz,
    const float* __restrict__ out_w, const float* __restrict__ ynorm,
    float* __restrict__ yp2)
{
  __shared__ float gs[128];
  __shared__ float rbuf[2][2];
  int p = blockIdx.x;
  int d = threadIdx.x;
  int h = p >> 7, w = p & 127;
  int pT = w*128 + h;
  float y = ys[(0*L + p )*128 + d] + ys[(2*L + p )*128 + d]
          + ys[(1*L + pT)*128 + d] + ys[(3*L + pT)*128 + d];
  float sumD = Ds[d] + Ds[128 + d] + Ds[256 + d] + Ds[384 + d];
  y = fmaf(u_row[p*128 + d], sumD, y);
  float s = wave_sum(y);
  float sq = wave_sum(y*y);
  if ((d & 63) == 0){ rbuf[d>>6][0] = s; rbuf[d>>6][1] = sq; }
  __syncthreads();
  float ts = rbuf[0][0] + rbuf[1][0];
  float tq = rbuf[0][1] + rbuf[1][1];
  float m = ts * (1.f/128.f);
  float va = tq * (1.f/128.f) - m*m;
  float yn = (y - m) * rsqrtf(va + 1e-5f) * on_g[d] + on_b[d];
  gs[d] = yn * sz[p*128 + d];
  __syncthreads();
  if (d < 64){
    const float4* wr = (const float4*)(out_w + d*128);
    const float4* gr = (const float4*)gs;
    float acc = 0.f;
    #pragma unroll
    for (int i = 0; i < 32; ++i){
      float4 a = gr[i], bw = wr[i];
      acc = fmaf(a.x, bw.x, acc); acc = fmaf(a.y, bw.y, acc);
      acc = fmaf(a.z, bw.z, acc); acc = fmaf(a.w, bw.w, acc);
    }
    yp2[p*64 + d] = ynorm[p*64 + d] + acc;
  }
}

// ---------------- K11: depthwise 3x3 (64ch, NHWC) + bias -------------------
__global__ __launch_bounds__(256) void k_dw2a(
    const float* __restrict__ yp2, const float* __restrict__ w,
    const float* __restrict__ b, float* __restrict__ t2)
{
  int g = blockIdx.x * 256 + threadIdx.x;   // 64 * 16384
  int c = g & 63;
  int p = g >> 6;
  int h = p >> 7, ww = p & 127;
  const float* wp = w + c*9;
  float acc = b[c];
  #pragma unroll
  for (int ky = 0; ky < 3; ++ky){
    int hh = h + ky - 1;
    if ((unsigned)hh < 128u){
      #pragma unroll
      for (int kx = 0; kx < 3; ++kx){
        int wx = ww + kx - 1;
        if ((unsigned)wx < 128u)
          acc = fmaf(yp2[(hh*128 + wx)*64 + c], wp[ky*3+kx], acc);
      }
    }
  }
  t2[p*64 + c] = acc;
}

// ---------------- K12: 1x1 64->64 + bias + relu + residual -----------------
__global__ __launch_bounds__(256) void k_dw2b(
    const float* __restrict__ t2, const float* __restrict__ w,
    const float* __restrict__ b, const float* __restrict__ x,
    float* __restrict__ out)
{
  __shared__ float s[16][65];
  int p0 = blockIdx.x * 16;
  for (int i = threadIdx.x; i < 1024; i += 256){
    int pix = i >> 6, c = i & 63;
    s[pix][c] = t2[(p0 + pix)*64 + c];
  }
  __syncthreads();
  int dp = threadIdx.x & 15, cg = threadIdx.x >> 4;
  #pragma unroll
  for (int cc = 0; cc < 4; ++cc){
    int c = cg + cc*16;
    float acc = b[c];
    const float* wp = w + c*64;
    #pragma unroll 8
    for (int i = 0; i < 64; ++i) acc = fmaf(s[dp][i], wp[i], acc);
    acc = fmaxf(acc, 0.f);
    int p = p0 + dp;
    out[c*L + p] = acc + x[c*L + p];
  }
}

extern "C" void kernel_launch(void* const* d_in, const int* in_sizes, int n_in,
                              void* d_out, int out_size, void* d_ws, size_t ws_size,
                              hipStream_t stream)
{
  const float* x       = (const float*)d_in[0];
  const float* conv1_w = (const float*)d_in[1];
  const float* conv1_b = (const float*)d_in[2];
  const float* conv2_w = (const float*)d_in[3];
  const float* conv2_b = (const float*)d_in[4];
  const float* dw1a_w  = (const float*)d_in[5];
  const float* dw1a_b  = (const float*)d_in[6];
  const float* dw1b_w  = (const float*)d_in[7];
  const float* dw1b_b  = (const float*)d_in[8];
  const float* dw2a_w  = (const float*)d_in[9];
  const float* dw2a_b  = (const float*)d_in[10];
  const float* dw2b_w  = (const float*)d_in[11];
  const float* dw2b_b  = (const float*)d_in[12];
  const float* ln_g    = (const float*)d_in[13];
  const float* ln_b    = (const float*)d_in[14];
  const float* ipw     = (const float*)d_in[15];
  const float* cdw_w   = (const float*)d_in[16];
  const float* cdw_b   = (const float*)d_in[17];
  const float* xw      = (const float*)d_in[18];
  const float* dtw     = (const float*)d_in[19];
  const float* dtb     = (const float*)d_in[20];
  const float* Alog    = (const float*)d_in[21];
  const float* DsArr   = (const float*)d_in[22];
  const float* on_g    = (const float*)d_in[23];
  const float* on_b    = (const float*)d_in[24];
  const float* out_w   = (const float*)d_in[25];
  float* out = (float*)d_out;

  char* ws = (char*)d_ws;
  const size_t MB = 1048576ull;
  float* y1      = (float*)(ws + 0*MB);    // 8MB   conv -> K2
  float* t1      = (float*)(ws + 8*MB);    // 8MB   K2 -> K3
  float* y2      = (float*)(ws + 16*MB);   // 4MB   K3 -> K4
  float* xa_pre  = (float*)(ws + 20*MB);   // 8MB   K4 -> K5
  float* wT1     = (float*)(ws + 28*MB);           // 144KB  prep -> conv  (dead after)
  float* wT2     = (float*)(ws + 28*MB + 524288);  // 400KB  prep -> conv
  float* ipwT    = (float*)(ws + 29*MB);           // 64KB   prep -> K4
  float* ysb     = (float*)(ws + 0*MB);    // 32MB  K9 -> K10 (reuses 0-32MB, all dead)
  float* delta_s = (float*)(ws + 32*MB);   // 32MB  K6 -> K7/K9
  float* ynorm   = (float*)(ws + 64*MB);   // 4MB   K4 -> K10
  float* sz      = (float*)(ws + 68*MB);   // 8MB   K4 -> K10
  float* u       = (float*)(ws + 76*MB);   // 8MB   K5 -> K6
  float* u_row   = (float*)(ws + 84*MB);   // 8MB   K6 -> K7/K9/K10
  float* u_col   = (float*)(ws + 92*MB);   // 8MB   K6 -> K7/K9
  float* Bsb     = (float*)(ws + 100*MB);  // 4MB   K6 -> K7/K9
  float* Csb     = (float*)(ws + 104*MB);  // 4MB   K6 -> K9
  float* Pb      = (float*)(ws + 108*MB);  // 2MB   K7 -> K8
  float* Sb      = (float*)(ws + 110*MB);  // 2MB   K7 -> K8
  float* hst     = (float*)(ws + 112*MB);  // 2MB   K8 -> K9
  float* yp2     = (float*)(ws + 114*MB);  // 4MB   K10 -> K11
  float* t2      = (float*)(ws + 118*MB);  // 4MB   K11 -> K12
  float* red     = (float*)(ws + 122*MB);  // 8B    K3 -> K4

  hipMemsetAsync(red, 0, 2*sizeof(float), stream);

  k_prep   <<<608, 256, 0, stream>>>(conv1_w, conv2_w, ipw, wT1, wT2, ipwT);
  k_convA<3><<<512, 256, 0, stream>>>(x, wT1, conv1_b, y1);
  k_convA<5><<<512, 256, 0, stream>>>(x, wT2, conv2_b, y1 + 64*L);
  k_dw1a  <<<8192, 256, 0, stream>>>(y1, dw1a_w, dw1a_b, t1);
  k_dw1b  <<<1024, 256, 0, stream>>>(t1, dw1b_w, dw1b_b, y2, red);
  k_norm_inproj<<<512, 256, 0, stream>>>(y2, red, ln_g, ln_b, ipwT, ynorm, xa_pre, sz);
  k_dwc   <<<8192, 256, 0, stream>>>(xa_pre, cdw_w, cdw_b, u);
  k_proj<0><<<1024, 256, 0, stream>>>(u, xw, dtw, dtb, delta_s, Bsb, Csb, u_row);
  k_proj<1><<<1024, 256, 0, stream>>>(u, xw, dtw, dtb, delta_s, Bsb, Csb, u_col);
  k_scan1 <<<256, 128, 0, stream>>>(delta_s, u_row, u_col, Bsb, Alog, Pb, Sb);
  k_scan2 <<<32, 256, 0, stream>>>(Pb, Sb, hst);
  k_scan3 <<<256, 128, 0, stream>>>(delta_s, u_row, u_col, Bsb, Csb, Alog, hst, ysb);
  k_combine<<<16384, 128, 0, stream>>>(ysb, u_row, DsArr, on_g, on_b, sz, out_w, ynorm, yp2);
  k_dw2a  <<<4096, 256, 0, stream>>>(yp2, dw2a_w, dw2a_b, t2);
  k_dw2b  <<<1024, 256, 0, stream>>>(t2, dw2b_w, dw2b_b, x, out);
}

// Round 6
// 891.255 us; speedup vs baseline: 1.4937x; 1.0322x over previous
//
#include <hip/hip_runtime.h>

#define L 16384

__device__ __forceinline__ float softplusf(float x){
  return (x > 20.f) ? x : log1pf(__expf(x));
}
__device__ __forceinline__ float siluf(float x){
  return x / (1.f + __expf(-x));
}
__device__ __forceinline__ float wave_sum(float v){
  #pragma unroll
  for (int o = 32; o; o >>= 1) v += __shfl_xor(v, o);
  return v;
}

// ---------------- K0: prep — weight transposes ------------------------------
// wT1[ci][co][9], wT2[ci][co][25] (taps contiguous per (ci,co) -> scalar loads)
// ipwT[c][e] (256 contiguous e per c)
__global__ __launch_bounds__(256) void k_prep(
    const float* __restrict__ w1, const float* __restrict__ w2,
    const float* __restrict__ ipw,
    float* __restrict__ wT1, float* __restrict__ wT2, float* __restrict__ ipwT)
{
  int g = blockIdx.x * 256 + threadIdx.x;
  if (g < 36864){                       // 64*64*9
    int ci = g / 576, rem = g % 576, co = rem / 9, tap = rem % 9;
    wT1[g] = w1[(co*64 + ci)*9 + tap];
  } else if (g < 36864 + 102400){       // 64*64*25
    int g2 = g - 36864;
    int ci = g2 / 1600, rem = g2 % 1600, co = rem / 25, tap = rem % 25;
    wT2[g2] = w2[(co*64 + ci)*25 + tap];
  } else if (g < 36864 + 102400 + 16384){
    int g3 = g - 139264;
    int e = g3 & 255, c = g3 >> 8;
    ipwT[g3] = ipw[e*64 + c];
  }
}

// ---------------- K1: dense conv 64->64, relu. lane=pixel, scalar weights --
// Block: 256 thr = 2 image rows (128 cols each); covers 4 output channels.
// Grid: 16 co-groups x 64 row-pairs = 1024 blocks -> 16 waves/CU.
// x loads coalesced per-lane; weight loads wave-uniform -> SGPR broadcast.
template<int KS>
__global__ __launch_bounds__(256) void k_convB(
    const float* __restrict__ x, const float* __restrict__ wT,
    const float* __restrict__ b, float* __restrict__ y)
{
  constexpr int P = KS/2, NT = KS*KS;
  const int tid  = threadIdx.x;
  const int col  = tid & 127;
  const int rsub = tid >> 7;
  const int cg   = blockIdx.x & 15;
  const int rp   = blockIdx.x >> 4;
  const int row  = rp*2 + rsub;
  const int co0  = cg*4;
  float acc[4] = {b[co0], b[co0+1], b[co0+2], b[co0+3]};
  for (int ci = 0; ci < 64; ++ci){
    const float* xp = x + ci*L;
    const float* wp = wT + (ci*64 + co0)*NT;
    #pragma unroll
    for (int ky = 0; ky < KS; ++ky){
      int hh = row + ky - P;
      if ((unsigned)hh < 128u){
        const float* xr = xp + hh*128;
        #pragma unroll
        for (int kx = 0; kx < KS; ++kx){
          int cc = col + kx - P;
          float xv = ((unsigned)cc < 128u) ? xr[cc] : 0.f;
          #pragma unroll
          for (int a = 0; a < 4; ++a)
            acc[a] = fmaf(xv, wp[a*NT + ky*KS + kx], acc[a]);
        }
      }
    }
  }
  const int p = row*128 + col;
  #pragma unroll
  for (int a = 0; a < 4; ++a)
    y[(co0+a)*L + p] = fmaxf(acc[a], 0.f);
}

// ---------------- K2: grouped conv dw1a (128ch, groups=64, 2in/2out, 3x3) ---
__global__ __launch_bounds__(256) void k_dw1a(
    const float* __restrict__ y1, const float* __restrict__ w, const float* __restrict__ b,
    float* __restrict__ t1)
{
  int g = blockIdx.x * 256 + threadIdx.x;      // 128 * 16384 threads
  int p = g & (L-1);
  int o = g >> 14;
  int h = p >> 7, ww = p & 127;
  int grp = o >> 1;
  float acc = b[o];
  #pragma unroll
  for (int i = 0; i < 2; ++i){
    const float* xp = y1 + (grp*2 + i)*L;
    const float* wp = w + (o*2 + i)*9;
    #pragma unroll
    for (int ky = 0; ky < 3; ++ky){
      int hh = h + ky - 1;
      if ((unsigned)hh < 128u){
        #pragma unroll
        for (int kx = 0; kx < 3; ++kx){
          int wx = ww + kx - 1;
          if ((unsigned)wx < 128u)
            acc = fmaf(xp[hh*128 + wx], wp[ky*3+kx], acc);
        }
      }
    }
  }
  t1[o*L + p] = acc;
}

// ---------------- K3: 1x1 conv 128->64 + bias + relu + global sum/sumsq ----
__global__ __launch_bounds__(256) void k_dw1b(
    const float* __restrict__ t1, const float* __restrict__ w, const float* __restrict__ b,
    float* __restrict__ y2, float* __restrict__ red)
{
  __shared__ float s[16][130];
  __shared__ float rs[4][2];
  int p0 = blockIdx.x * 16;
  for (int i = threadIdx.x; i < 2048; i += 256){
    int ci = i >> 4, dp = i & 15;
    s[dp][ci] = t1[ci*L + p0 + dp];
  }
  __syncthreads();
  int dp = threadIdx.x & 15, cg = threadIdx.x >> 4;
  float lsum = 0.f, lsq = 0.f;
  #pragma unroll
  for (int cc = 0; cc < 4; ++cc){
    int c = cg + cc*16;
    float acc = b[c];
    const float* wp = w + c*128;
    #pragma unroll 8
    for (int i = 0; i < 128; ++i) acc = fmaf(s[dp][i], wp[i], acc);
    acc = fmaxf(acc, 0.f);
    y2[c*L + p0 + dp] = acc;
    lsum += acc; lsq += acc*acc;
  }
  lsum = wave_sum(lsum); lsq = wave_sum(lsq);
  if ((threadIdx.x & 63) == 0){ rs[threadIdx.x>>6][0] = lsum; rs[threadIdx.x>>6][1] = lsq; }
  __syncthreads();
  if (threadIdx.x == 0){
    float a = rs[0][0]+rs[1][0]+rs[2][0]+rs[3][0];
    float q = rs[0][1]+rs[1][1]+rs[2][1]+rs[3][1];
    atomicAdd(&red[0], a);
    atomicAdd(&red[1], q);
  }
}

// ------- K4: global norm + LN(64) + in_proj (64->256), LDS-staged weights --
__global__ __launch_bounds__(256) void k_norm_inproj(
    const float* __restrict__ y2, const float* __restrict__ red,
    const float* __restrict__ ln_g, const float* __restrict__ ln_b,
    const float* __restrict__ ipwT,
    float* __restrict__ ynorm, float* __restrict__ xa_pre, float* __restrict__ sz)
{
  __shared__ float ws_s[16384];     // [c][e] 64x256
  __shared__ float ls_s[64*33];     // [c][pix] stride 33
  __shared__ float mv_s[2][32];
  const int tid = threadIdx.x;
  const int p0 = blockIdx.x * 32;
  {
    const float4* src = (const float4*)ipwT;
    float4* dst = (float4*)ws_s;
    #pragma unroll
    for (int i = 0; i < 16; ++i) dst[tid + i*256] = src[tid + i*256];
  }
  const float invN = 1.f / 1048576.f;
  float mu = red[0] * invN;
  float var = red[1] * invN - mu*mu;
  float rsg = rsqrtf(var + 1e-5f);
  for (int i = tid; i < 2048; i += 256){
    int c = i >> 5, pix = i & 31;
    ls_s[c*33 + pix] = (y2[c*L + p0 + pix] - mu) * rsg;
  }
  __syncthreads();
  for (int i = tid; i < 2048; i += 256){
    int pix = i >> 6, c = i & 63;
    ynorm[(p0 + pix)*64 + c] = ls_s[c*33 + pix];
  }
  if (tid < 32){
    float s = 0.f, q = 0.f;
    #pragma unroll 8
    for (int c = 0; c < 64; ++c){
      float v = ls_s[c*33 + tid];
      s += v; q += v*v;
    }
    float m = s * (1.f/64.f);
    float va = q * (1.f/64.f) - m*m;
    mv_s[0][tid] = m;
    mv_s[1][tid] = rsqrtf(va + 1e-5f);
  }
  __syncthreads();
  for (int i = tid; i < 2048; i += 256){
    int c = i >> 5, pix = i & 31;
    float v = ls_s[c*33 + pix];
    ls_s[c*33 + pix] = (v - mv_s[0][pix]) * mv_s[1][pix] * ln_g[c] + ln_b[c];
  }
  __syncthreads();
  const int pix = tid & 31, eh = tid >> 5;
  float acc[32];
  #pragma unroll
  for (int j = 0; j < 32; ++j) acc[j] = 0.f;
  for (int c = 0; c < 64; ++c){
    float lnv = ls_s[c*33 + pix];
    const float4* w4 = (const float4*)(ws_s + c*256 + eh*32);
    #pragma unroll
    for (int j = 0; j < 8; ++j){
      float4 wq = w4[j];
      acc[j*4+0] = fmaf(lnv, wq.x, acc[j*4+0]);
      acc[j*4+1] = fmaf(lnv, wq.y, acc[j*4+1]);
      acc[j*4+2] = fmaf(lnv, wq.z, acc[j*4+2]);
      acc[j*4+3] = fmaf(lnv, wq.w, acc[j*4+3]);
    }
  }
  __syncthreads();
  float* szs = ws_s; // [pix][129]
  const int p = p0 + pix;
  if (eh < 4){
    const int e0 = eh*32;
    #pragma unroll
    for (int j = 0; j < 32; ++j)
      xa_pre[(e0+j)*L + p] = acc[j];
  } else {
    const int j0 = (eh-4)*32;
    #pragma unroll
    for (int j = 0; j < 32; ++j)
      szs[pix*129 + j0 + j] = siluf(acc[j]);
  }
  __syncthreads();
  for (int i = tid; i < 32*128; i += 256){
    int pix2 = i >> 7, j = i & 127;
    sz[(p0 + pix2)*128 + j] = szs[pix2*129 + j];
  }
}

// ---------------- K5: depthwise 3x3 (128ch) + bias + silu ------------------
__global__ __launch_bounds__(256) void k_dwc(
    const float* __restrict__ xa, const float* __restrict__ w, const float* __restrict__ b,
    float* __restrict__ u)
{
  int g = blockIdx.x * 256 + threadIdx.x;
  int p = g & (L-1);
  int d = g >> 14;
  int h = p >> 7, ww = p & 127;
  const float* xp = xa + d*L;
  const float* wp = w + d*9;
  float acc = b[d];
  #pragma unroll
  for (int ky = 0; ky < 3; ++ky){
    int hh = h + ky - 1;
    if ((unsigned)hh < 128u){
      #pragma unroll
      for (int kx = 0; kx < 3; ++kx){
        int wx = ww + kx - 1;
        if ((unsigned)wx < 128u)
          acc = fmaf(xp[hh*128 + wx], wp[ky*3+kx], acc);
      }
    }
  }
  u[d*L + p] = siluf(acc);
}

// ------- K6: per-pixel x_proj (128->36) + delta softplus, scan-order store -
template<int PASS>  // PASS 0: k={0,2}, row-major idx=p ; PASS 1: k={1,3}, idx = w*128+h
__global__ __launch_bounds__(256) void k_proj(
    const float* __restrict__ u, const float* __restrict__ xw,
    const float* __restrict__ dtw, const float* __restrict__ dtb,
    float* __restrict__ delta_s, float* __restrict__ Bs, float* __restrict__ Cs,
    float* __restrict__ u_out)
{
  __shared__ float us[16][132];
  __shared__ float dts[16][2][4];
  int bb = blockIdx.x;
  int tid = threadIdx.x;
  for (int i = tid; i < 16*128; i += 256){
    int d = i >> 4, pix = i & 15;
    int idx = bb*16 + pix;
    int p;
    if (PASS == 0) p = idx;
    else           p = (idx & 127)*128 + (idx >> 7);
    us[pix][d] = u[d*L + p];
  }
  __syncthreads();
  for (int o = tid; o < 1152; o += 256){
    int pix = o / 72; int r = o % 72; int kk = r / 36; int c = r % 36;
    int k = (PASS == 0) ? kk*2 : kk*2 + 1;
    const float4* ur = (const float4*)(&us[pix][0]);
    const float4* wr = (const float4*)(xw + (k*36 + c)*128);
    float acc = 0.f;
    #pragma unroll
    for (int i = 0; i < 32; ++i){
      float4 a = ur[i], bw = wr[i];
      acc = fmaf(a.x, bw.x, acc); acc = fmaf(a.y, bw.y, acc);
      acc = fmaf(a.z, bw.z, acc); acc = fmaf(a.w, bw.w, acc);
    }
    int idx = bb*16 + pix;
    if (c < 4)        dts[pix][kk][c] = acc;
    else if (c < 20)  Bs[(k*L + idx)*16 + (c-4)]  = acc;
    else              Cs[(k*L + idx)*16 + (c-20)] = acc;
  }
  __syncthreads();
  int d = tid & 127, ph = tid >> 7;
  #pragma unroll
  for (int pp = 0; pp < 8; ++pp){
    int pix = pp*2 + ph;
    int idx = bb*16 + pix;
    #pragma unroll
    for (int kk = 0; kk < 2; ++kk){
      int k = (PASS == 0) ? kk*2 : kk*2 + 1;
      const float4 dw = *((const float4*)(dtw + (k*128 + d)*4));
      float acc = dtb[k*128 + d];
      acc = fmaf(dts[pix][kk][0], dw.x, acc);
      acc = fmaf(dts[pix][kk][1], dw.y, acc);
      acc = fmaf(dts[pix][kk][2], dw.z, acc);
      acc = fmaf(dts[pix][kk][3], dw.w, acc);
      delta_s[(k*L + idx)*128 + d] = softplusf(acc);
    }
    u_out[idx*128 + d] = us[pix][d];
  }
}

// ---------------- K7: scan pass 1 — per-chunk (prod a, local h) ------------
__global__ __launch_bounds__(128) void k_scan1(
    const float* __restrict__ delta_s, const float* __restrict__ u_row,
    const float* __restrict__ u_col, const float* __restrict__ Bs,
    const float* __restrict__ Alog, float* __restrict__ P, float* __restrict__ S)
{
  int blk = blockIdx.x;          // k*64 + chunk
  int k = blk >> 6, ch = blk & 63;
  int d = threadIdx.x;
  const float* u_s = (k & 1) ? u_col : u_row;
  float A[16], Pv[16], Sv[16];
  #pragma unroll
  for (int n = 0; n < 16; ++n){
    A[n] = -__expf(Alog[(k*128 + d)*16 + n]);
    Pv[n] = 1.f; Sv[n] = 0.f;
  }
  int base = ch*256;
  for (int t = 0; t < 256; ++t){
    int tl = base + t;
    int pos = (k < 2) ? tl : (L-1 - tl);
    float dl = delta_s[(k*L + pos)*128 + d];
    float du = dl * u_s[pos*128 + d];
    const float* Br = Bs + (k*L + pos)*16;
    #pragma unroll
    for (int n = 0; n < 16; ++n){
      float a = __expf(dl * A[n]);
      Sv[n] = fmaf(Sv[n], a, du * Br[n]);
      Pv[n] *= a;
    }
  }
  #pragma unroll
  for (int n = 0; n < 16; ++n){
    int o = (blk*16 + n)*128 + d;
    P[o] = Pv[n]; S[o] = Sv[n];
  }
}

// ---------------- K8: scan pass 2 — sequential over 64 chunks --------------
__global__ __launch_bounds__(256) void k_scan2(
    const float* __restrict__ P, const float* __restrict__ S, float* __restrict__ hst)
{
  int g = blockIdx.x * 256 + threadIdx.x;   // 8192 threads: k*2048 + n*128 + d
  int d = g & 127, n = (g >> 7) & 15, k = g >> 11;
  float h = 0.f;
  for (int c = 0; c < 64; ++c){
    int o = (((k*64 + c)*16) + n)*128 + d;
    hst[o] = h;
    h = fmaf(P[o], h, S[o]);
  }
}

// ---------------- K9: scan pass 3 — outputs with corrected h_start ---------
__global__ __launch_bounds__(128) void k_scan3(
    const float* __restrict__ delta_s, const float* __restrict__ u_row,
    const float* __restrict__ u_col, const float* __restrict__ Bs,
    const float* __restrict__ Cs, const float* __restrict__ Alog,
    const float* __restrict__ hst, float* __restrict__ ys)
{
  int blk = blockIdx.x;
  int k = blk >> 6, ch = blk & 63;
  int d = threadIdx.x;
  const float* u_s = (k & 1) ? u_col : u_row;
  float A[16], h[16];
  #pragma unroll
  for (int n = 0; n < 16; ++n){
    A[n] = -__expf(Alog[(k*128 + d)*16 + n]);
    h[n] = hst[(blk*16 + n)*128 + d];
  }
  int base = ch*256;
  for (int t = 0; t < 256; ++t){
    int tl = base + t;
    int pos = (k < 2) ? tl : (L-1 - tl);
    float dl = delta_s[(k*L + pos)*128 + d];
    float du = dl * u_s[pos*128 + d];
    const float* Br = Bs + (k*L + pos)*16;
    const float* Cr = Cs + (k*L + pos)*16;
    float y = 0.f;
    #pragma unroll
    for (int n = 0; n < 16; ++n){
      float a = __expf(dl * A[n]);
      h[n] = fmaf(h[n], a, du * Br[n]);
      y = fmaf(h[n], Cr[n], y);
    }
    ys[(k*L + pos)*128 + d] = y;
  }
}

// ------- K10: combine 4 dirs + u*sumD + LN(128) + gate + out_proj + add ----
__global__ __launch_bounds__(128) void k_combine(
    const float* __restrict__ ys, const float* __restrict__ u_row,
    const float* __restrict__ Ds, const float* __restrict__ on_g,
    const float* __restrict__ on_b, const float* __restrict__ sz,
    const float* __restrict__ out_w, const float* __restrict__ ynorm,
    float* __restrict__ yp2)
{
  __shared__ float gs[128];
  __shared__ float rbuf[2][2];
  int p = blockIdx.x;
  int d = threadIdx.x;
  int h = p >> 7, w = p & 127;
  int pT = w*128 + h;
  float y = ys[(0*L + p )*128 + d] + ys[(2*L + p )*128 + d]
          + ys[(1*L + pT)*128 + d] + ys[(3*L + pT)*128 + d];
  float sumD = Ds[d] + Ds[128 + d] + Ds[256 + d] + Ds[384 + d];
  y = fmaf(u_row[p*128 + d], sumD, y);
  float s = wave_sum(y);
  float sq = wave_sum(y*y);
  if ((d & 63) == 0){ rbuf[d>>6][0] = s; rbuf[d>>6][1] = sq; }
  __syncthreads();
  float ts = rbuf[0][0] + rbuf[1][0];
  float tq = rbuf[0][1] + rbuf[1][1];
  float m = ts * (1.f/128.f);
  float va = tq * (1.f/128.f) - m*m;
  float yn = (y - m) * rsqrtf(va + 1e-5f) * on_g[d] + on_b[d];
  gs[d] = yn * sz[p*128 + d];
  __syncthreads();
  if (d < 64){
    const float4* wr = (const float4*)(out_w + d*128);
    const float4* gr = (const float4*)gs;
    float acc = 0.f;
    #pragma unroll
    for (int i = 0; i < 32; ++i){
      float4 a = gr[i], bw = wr[i];
      acc = fmaf(a.x, bw.x, acc); acc = fmaf(a.y, bw.y, acc);
      acc = fmaf(a.z, bw.z, acc); acc = fmaf(a.w, bw.w, acc);
    }
    yp2[p*64 + d] = ynorm[p*64 + d] + acc;
  }
}

// ---------------- K11: depthwise 3x3 (64ch, NHWC) + bias -------------------
__global__ __launch_bounds__(256) void k_dw2a(
    const float* __restrict__ yp2, const float* __restrict__ w,
    const float* __restrict__ b, float* __restrict__ t2)
{
  int g = blockIdx.x * 256 + threadIdx.x;   // 64 * 16384
  int c = g & 63;
  int p = g >> 6;
  int h = p >> 7, ww = p & 127;
  const float* wp = w + c*9;
  float acc = b[c];
  #pragma unroll
  for (int ky = 0; ky < 3; ++ky){
    int hh = h + ky - 1;
    if ((unsigned)hh < 128u){
      #pragma unroll
      for (int kx = 0; kx < 3; ++kx){
        int wx = ww + kx - 1;
        if ((unsigned)wx < 128u)
          acc = fmaf(yp2[(hh*128 + wx)*64 + c], wp[ky*3+kx], acc);
      }
    }
  }
  t2[p*64 + c] = acc;
}

// ---------------- K12: 1x1 64->64 + bias + relu + residual -----------------
__global__ __launch_bounds__(256) void k_dw2b(
    const float* __restrict__ t2, const float* __restrict__ w,
    const float* __restrict__ b, const float* __restrict__ x,
    float* __restrict__ out)
{
  __shared__ float s[16][65];
  int p0 = blockIdx.x * 16;
  for (int i = threadIdx.x; i < 1024; i += 256){
    int pix = i >> 6, c = i & 63;
    s[pix][c] = t2[(p0 + pix)*64 + c];
  }
  __syncthreads();
  int dp = threadIdx.x & 15, cg = threadIdx.x >> 4;
  #pragma unroll
  for (int cc = 0; cc < 4; ++cc){
    int c = cg + cc*16;
    float acc = b[c];
    const float* wp = w + c*64;
    #pragma unroll 8
    for (int i = 0; i < 64; ++i) acc = fmaf(s[dp][i], wp[i], acc);
    acc = fmaxf(acc, 0.f);
    int p = p0 + dp;
    out[c*L + p] = acc + x[c*L + p];
  }
}

extern "C" void kernel_launch(void* const* d_in, const int* in_sizes, int n_in,
                              void* d_out, int out_size, void* d_ws, size_t ws_size,
                              hipStream_t stream)
{
  const float* x       = (const float*)d_in[0];
  const float* conv1_w = (const float*)d_in[1];
  const float* conv1_b = (const float*)d_in[2];
  const float* conv2_w = (const float*)d_in[3];
  const float* conv2_b = (const float*)d_in[4];
  const float* dw1a_w  = (const float*)d_in[5];
  const float* dw1a_b  = (const float*)d_in[6];
  const float* dw1b_w  = (const float*)d_in[7];
  const float* dw1b_b  = (const float*)d_in[8];
  const float* dw2a_w  = (const float*)d_in[9];
  const float* dw2a_b  = (const float*)d_in[10];
  const float* dw2b_w  = (const float*)d_in[11];
  const float* dw2b_b  = (const float*)d_in[12];
  const float* ln_g    = (const float*)d_in[13];
  const float* ln_b    = (const float*)d_in[14];
  const float* ipw     = (const float*)d_in[15];
  const float* cdw_w   = (const float*)d_in[16];
  const float* cdw_b   = (const float*)d_in[17];
  const float* xw      = (const float*)d_in[18];
  const float* dtw     = (const float*)d_in[19];
  const float* dtb     = (const float*)d_in[20];
  const float* Alog    = (const float*)d_in[21];
  const float* DsArr   = (const float*)d_in[22];
  const float* on_g    = (const float*)d_in[23];
  const float* on_b    = (const float*)d_in[24];
  const float* out_w   = (const float*)d_in[25];
  float* out = (float*)d_out;

  char* ws = (char*)d_ws;
  const size_t MB = 1048576ull;
  float* y1      = (float*)(ws + 0*MB);    // 8MB   conv -> K2
  float* t1      = (float*)(ws + 8*MB);    // 8MB   K2 -> K3
  float* y2      = (float*)(ws + 16*MB);   // 4MB   K3 -> K4
  float* xa_pre  = (float*)(ws + 20*MB);   // 8MB   K4 -> K5
  float* wT1     = (float*)(ws + 28*MB);           // 144KB  prep -> conv
  float* wT2     = (float*)(ws + 28*MB + 524288);  // 400KB  prep -> conv
  float* ipwT    = (float*)(ws + 29*MB);           // 64KB   prep -> K4
  float* ysb     = (float*)(ws + 0*MB);    // 32MB  K9 -> K10 (reuses 0-32MB)
  float* delta_s = (float*)(ws + 32*MB);   // 32MB  K6 -> K7/K9
  float* ynorm   = (float*)(ws + 64*MB);   // 4MB   K4 -> K10
  float* sz      = (float*)(ws + 68*MB);   // 8MB   K4 -> K10
  float* u       = (float*)(ws + 76*MB);   // 8MB   K5 -> K6
  float* u_row   = (float*)(ws + 84*MB);   // 8MB   K6 -> K7/K9/K10
  float* u_col   = (float*)(ws + 92*MB);   // 8MB   K6 -> K7/K9
  float* Bsb     = (float*)(ws + 100*MB);  // 4MB   K6 -> K7/K9
  float* Csb     = (float*)(ws + 104*MB);  // 4MB   K6 -> K9
  float* Pb      = (float*)(ws + 108*MB);  // 2MB   K7 -> K8
  float* Sb      = (float*)(ws + 110*MB);  // 2MB   K7 -> K8
  float* hst     = (float*)(ws + 112*MB);  // 2MB   K8 -> K9
  float* yp2     = (float*)(ws + 114*MB);  // 4MB   K10 -> K11
  float* t2      = (float*)(ws + 118*MB);  // 4MB   K11 -> K12
  float* red     = (float*)(ws + 122*MB);  // 8B    K3 -> K4

  hipMemsetAsync(red, 0, 2*sizeof(float), stream);

  k_prep    <<<608, 256, 0, stream>>>(conv1_w, conv2_w, ipw, wT1, wT2, ipwT);
  k_convB<3><<<1024, 256, 0, stream>>>(x, wT1, conv1_b, y1);
  k_convB<5><<<1024, 256, 0, stream>>>(x, wT2, conv2_b, y1 + 64*L);
  k_dw1a  <<<8192, 256, 0, stream>>>(y1, dw1a_w, dw1a_b, t1);
  k_dw1b  <<<1024, 256, 0, stream>>>(t1, dw1b_w, dw1b_b, y2, red);
  k_norm_inproj<<<512, 256, 0, stream>>>(y2, red, ln_g, ln_b, ipwT, ynorm, xa_pre, sz);
  k_dwc   <<<8192, 256, 0, stream>>>(xa_pre, cdw_w, cdw_b, u);
  k_proj<0><<<1024, 256, 0, stream>>>(u, xw, dtw, dtb, delta_s, Bsb, Csb, u_row);
  k_proj<1><<<1024, 256, 0, stream>>>(u, xw, dtw, dtb, delta_s, Bsb, Csb, u_col);
  k_scan1 <<<256, 128, 0, stream>>>(delta_s, u_row, u_col, Bsb, Alog, Pb, Sb);
  k_scan2 <<<32, 256, 0, stream>>>(Pb, Sb, hst);
  k_scan3 <<<256, 128, 0, stream>>>(delta_s, u_row, u_col, Bsb, Csb, Alog, hst, ysb);
  k_combine<<<16384, 128, 0, stream>>>(ysb, u_row, DsArr, on_g, on_b, sz, out_w, ynorm, yp2);
  k_dw2a  <<<4096, 256, 0, stream>>>(yp2, dw2a_w, dw2a_b, t2);
  k_dw2b  <<<1024, 256, 0, stream>>>(t2, dw2b_w, dw2b_b, x, out);
}

// Round 7
// 745.705 us; speedup vs baseline: 1.7853x; 1.1952x over previous
//
#include <hip/hip_runtime.h>

#define L 16384
#define NCH 128   // scan chunks per direction
#define CT  128   // chunk length (L/NCH)

__device__ __forceinline__ float softplusf(float x){
  return (x > 20.f) ? x : log1pf(__expf(x));
}
__device__ __forceinline__ float siluf(float x){
  return x / (1.f + __expf(-x));
}
__device__ __forceinline__ float wave_sum(float v){
  #pragma unroll
  for (int o = 32; o; o >>= 1) v += __shfl_xor(v, o);
  return v;
}

// ---------------- K0: prep — weight transposes ------------------------------
__global__ __launch_bounds__(256) void k_prep(
    const float* __restrict__ w1, const float* __restrict__ w2,
    const float* __restrict__ ipw,
    float* __restrict__ wT1, float* __restrict__ wT2, float* __restrict__ ipwT)
{
  int g = blockIdx.x * 256 + threadIdx.x;
  if (g < 36864){                       // 64*64*9
    int ci = g / 576, rem = g % 576, co = rem / 9, tap = rem % 9;
    wT1[g] = w1[(co*64 + ci)*9 + tap];
  } else if (g < 36864 + 102400){       // 64*64*25
    int g2 = g - 36864;
    int ci = g2 / 1600, rem = g2 % 1600, co = rem / 25, tap = rem % 25;
    wT2[g2] = w2[(co*64 + ci)*25 + tap];
  } else if (g < 36864 + 102400 + 16384){
    int g3 = g - 139264;
    int e = g3 & 255, c = g3 >> 8;
    ipwT[g3] = ipw[e*64 + c];
  }
}

// ---------------- K1: dense conv 64->64, relu. 2 rows x 4 co per thread ----
// lane=col (coalesced x), weights wave-uniform (scalar). Vertical reuse:
// (KS+1) input rows feed 2 output rows -> 30 loads / 200 FMA per ci (5x5).
// Grid: 16 co-groups x 32 row-quads = 512 blocks; block = 128 col x 2 rowpair.
template<int KS>
__global__ __launch_bounds__(256) void k_convC(
    const float* __restrict__ x, const float* __restrict__ wT,
    const float* __restrict__ b, float* __restrict__ y)
{
  constexpr int P = KS/2, NT = KS*KS;
  const int tid = threadIdx.x;
  const int col = tid & 127;
  const int rh  = tid >> 7;
  const int cg  = blockIdx.x & 15;
  const int rq  = blockIdx.x >> 4;
  const int r0  = rq*4 + rh*2;        // rows r0, r0+1
  const int co0 = cg*4;
  float acc[2][4];
  #pragma unroll
  for (int a = 0; a < 4; ++a){ acc[0][a] = b[co0+a]; acc[1][a] = acc[0][a]; }

  for (int ci = 0; ci < 64; ++ci){
    const float* xp = x + ci*L;
    const float* wp = wT + (ci*64 + co0)*NT;
    #pragma unroll
    for (int ir = 0; ir < KS+1; ++ir){
      int gr = r0 - P + ir;
      float xrow[KS];
      if ((unsigned)gr < 128u){
        const float* xr = xp + gr*128;
        #pragma unroll
        for (int kx = 0; kx < KS; ++kx){
          int cc = col + kx - P;
          xrow[kx] = ((unsigned)cc < 128u) ? xr[cc] : 0.f;
        }
      } else {
        #pragma unroll
        for (int kx = 0; kx < KS; ++kx) xrow[kx] = 0.f;
      }
      #pragma unroll
      for (int q = 0; q < 2; ++q){
        int ky = ir - q;
        if (ky >= 0 && ky < KS){
          #pragma unroll
          for (int kx = 0; kx < KS; ++kx){
            #pragma unroll
            for (int a = 0; a < 4; ++a)
              acc[q][a] = fmaf(xrow[kx], wp[a*NT + ky*KS + kx], acc[q][a]);
          }
        }
      }
    }
  }
  #pragma unroll
  for (int q = 0; q < 2; ++q){
    const int p = (r0+q)*128 + col;
    #pragma unroll
    for (int a = 0; a < 4; ++a)
      y[(co0+a)*L + p] = fmaxf(acc[q][a], 0.f);
  }
}

// ---------------- K2: grouped conv dw1a (128ch, groups=64, 2in/2out, 3x3) ---
__global__ __launch_bounds__(256) void k_dw1a(
    const float* __restrict__ y1, const float* __restrict__ w, const float* __restrict__ b,
    float* __restrict__ t1)
{
  int g = blockIdx.x * 256 + threadIdx.x;      // 128 * 16384 threads
  int p = g & (L-1);
  int o = g >> 14;
  int h = p >> 7, ww = p & 127;
  int grp = o >> 1;
  float acc = b[o];
  #pragma unroll
  for (int i = 0; i < 2; ++i){
    const float* xp = y1 + (grp*2 + i)*L;
    const float* wp = w + (o*2 + i)*9;
    #pragma unroll
    for (int ky = 0; ky < 3; ++ky){
      int hh = h + ky - 1;
      if ((unsigned)hh < 128u){
        #pragma unroll
        for (int kx = 0; kx < 3; ++kx){
          int wx = ww + kx - 1;
          if ((unsigned)wx < 128u)
            acc = fmaf(xp[hh*128 + wx], wp[ky*3+kx], acc);
        }
      }
    }
  }
  t1[o*L + p] = acc;
}

// ---------------- K3: 1x1 conv 128->64 + bias + relu + global sum/sumsq ----
__global__ __launch_bounds__(256) void k_dw1b(
    const float* __restrict__ t1, const float* __restrict__ w, const float* __restrict__ b,
    float* __restrict__ y2, float* __restrict__ red)
{
  __shared__ float s[16][130];
  __shared__ float rs[4][2];
  int p0 = blockIdx.x * 16;
  for (int i = threadIdx.x; i < 2048; i += 256){
    int ci = i >> 4, dp = i & 15;
    s[dp][ci] = t1[ci*L + p0 + dp];
  }
  __syncthreads();
  int dp = threadIdx.x & 15, cg = threadIdx.x >> 4;
  float lsum = 0.f, lsq = 0.f;
  #pragma unroll
  for (int cc = 0; cc < 4; ++cc){
    int c = cg + cc*16;
    float acc = b[c];
    const float* wp = w + c*128;
    #pragma unroll 8
    for (int i = 0; i < 128; ++i) acc = fmaf(s[dp][i], wp[i], acc);
    acc = fmaxf(acc, 0.f);
    y2[c*L + p0 + dp] = acc;
    lsum += acc; lsq += acc*acc;
  }
  lsum = wave_sum(lsum); lsq = wave_sum(lsq);
  if ((threadIdx.x & 63) == 0){ rs[threadIdx.x>>6][0] = lsum; rs[threadIdx.x>>6][1] = lsq; }
  __syncthreads();
  if (threadIdx.x == 0){
    float a = rs[0][0]+rs[1][0]+rs[2][0]+rs[3][0];
    float q = rs[0][1]+rs[1][1]+rs[2][1]+rs[3][1];
    atomicAdd(&red[0], a);
    atomicAdd(&red[1], q);
  }
}

// ------- K4: global norm + LN(64) + in_proj (64->256), LDS-staged weights --
__global__ __launch_bounds__(256) void k_norm_inproj(
    const float* __restrict__ y2, const float* __restrict__ red,
    const float* __restrict__ ln_g, const float* __restrict__ ln_b,
    const float* __restrict__ ipwT,
    float* __restrict__ ynorm, float* __restrict__ xa_pre, float* __restrict__ sz)
{
  __shared__ float ws_s[16384];     // [c][e] 64x256
  __shared__ float ls_s[64*33];     // [c][pix] stride 33
  __shared__ float mv_s[2][32];
  const int tid = threadIdx.x;
  const int p0 = blockIdx.x * 32;
  {
    const float4* src = (const float4*)ipwT;
    float4* dst = (float4*)ws_s;
    #pragma unroll
    for (int i = 0; i < 16; ++i) dst[tid + i*256] = src[tid + i*256];
  }
  const float invN = 1.f / 1048576.f;
  float mu = red[0] * invN;
  float var = red[1] * invN - mu*mu;
  float rsg = rsqrtf(var + 1e-5f);
  for (int i = tid; i < 2048; i += 256){
    int c = i >> 5, pix = i & 31;
    ls_s[c*33 + pix] = (y2[c*L + p0 + pix] - mu) * rsg;
  }
  __syncthreads();
  for (int i = tid; i < 2048; i += 256){
    int pix = i >> 6, c = i & 63;
    ynorm[(p0 + pix)*64 + c] = ls_s[c*33 + pix];
  }
  if (tid < 32){
    float s = 0.f, q = 0.f;
    #pragma unroll 8
    for (int c = 0; c < 64; ++c){
      float v = ls_s[c*33 + tid];
      s += v; q += v*v;
    }
    float m = s * (1.f/64.f);
    float va = q * (1.f/64.f) - m*m;
    mv_s[0][tid] = m;
    mv_s[1][tid] = rsqrtf(va + 1e-5f);
  }
  __syncthreads();
  for (int i = tid; i < 2048; i += 256){
    int c = i >> 5, pix = i & 31;
    float v = ls_s[c*33 + pix];
    ls_s[c*33 + pix] = (v - mv_s[0][pix]) * mv_s[1][pix] * ln_g[c] + ln_b[c];
  }
  __syncthreads();
  const int pix = tid & 31, eh = tid >> 5;
  float acc[32];
  #pragma unroll
  for (int j = 0; j < 32; ++j) acc[j] = 0.f;
  for (int c = 0; c < 64; ++c){
    float lnv = ls_s[c*33 + pix];
    const float4* w4 = (const float4*)(ws_s + c*256 + eh*32);
    #pragma unroll
    for (int j = 0; j < 8; ++j){
      float4 wq = w4[j];
      acc[j*4+0] = fmaf(lnv, wq.x, acc[j*4+0]);
      acc[j*4+1] = fmaf(lnv, wq.y, acc[j*4+1]);
      acc[j*4+2] = fmaf(lnv, wq.z, acc[j*4+2]);
      acc[j*4+3] = fmaf(lnv, wq.w, acc[j*4+3]);
    }
  }
  __syncthreads();
  float* szs = ws_s; // [pix][129]
  const int p = p0 + pix;
  if (eh < 4){
    const int e0 = eh*32;
    #pragma unroll
    for (int j = 0; j < 32; ++j)
      xa_pre[(e0+j)*L + p] = acc[j];
  } else {
    const int j0 = (eh-4)*32;
    #pragma unroll
    for (int j = 0; j < 32; ++j)
      szs[pix*129 + j0 + j] = siluf(acc[j]);
  }
  __syncthreads();
  for (int i = tid; i < 32*128; i += 256){
    int pix2 = i >> 7, j = i & 127;
    sz[(p0 + pix2)*128 + j] = szs[pix2*129 + j];
  }
}

// ---------------- K5: depthwise 3x3 (128ch) + bias + silu ------------------
__global__ __launch_bounds__(256) void k_dwc(
    const float* __restrict__ xa, const float* __restrict__ w, const float* __restrict__ b,
    float* __restrict__ u)
{
  int g = blockIdx.x * 256 + threadIdx.x;
  int p = g & (L-1);
  int d = g >> 14;
  int h = p >> 7, ww = p & 127;
  const float* xp = xa + d*L;
  const float* wp = w + d*9;
  float acc = b[d];
  #pragma unroll
  for (int ky = 0; ky < 3; ++ky){
    int hh = h + ky - 1;
    if ((unsigned)hh < 128u){
      #pragma unroll
      for (int kx = 0; kx < 3; ++kx){
        int wx = ww + kx - 1;
        if ((unsigned)wx < 128u)
          acc = fmaf(xp[hh*128 + wx], wp[ky*3+kx], acc);
      }
    }
  }
  u[d*L + p] = siluf(acc);
}

// ------- K6: per-pixel x_proj (128->36) + delta softplus, scan-order store -
template<int PASS>  // PASS 0: k={0,2}, row-major idx=p ; PASS 1: k={1,3}, idx = w*128+h
__global__ __launch_bounds__(256) void k_proj(
    const float* __restrict__ u, const float* __restrict__ xw,
    const float* __restrict__ dtw, const float* __restrict__ dtb,
    float* __restrict__ delta_s, float* __restrict__ Bs, float* __restrict__ Cs,
    float* __restrict__ u_out)
{
  __shared__ float us[16][132];
  __shared__ float dts[16][2][4];
  int bb = blockIdx.x;
  int tid = threadIdx.x;
  for (int i = tid; i < 16*128; i += 256){
    int d = i >> 4, pix = i & 15;
    int idx = bb*16 + pix;
    int p;
    if (PASS == 0) p = idx;
    else           p = (idx & 127)*128 + (idx >> 7);
    us[pix][d] = u[d*L + p];
  }
  __syncthreads();
  for (int o = tid; o < 1152; o += 256){
    int pix = o / 72; int r = o % 72; int kk = r / 36; int c = r % 36;
    int k = (PASS == 0) ? kk*2 : kk*2 + 1;
    const float4* ur = (const float4*)(&us[pix][0]);
    const float4* wr = (const float4*)(xw + (k*36 + c)*128);
    float acc = 0.f;
    #pragma unroll
    for (int i = 0; i < 32; ++i){
      float4 a = ur[i], bw = wr[i];
      acc = fmaf(a.x, bw.x, acc); acc = fmaf(a.y, bw.y, acc);
      acc = fmaf(a.z, bw.z, acc); acc = fmaf(a.w, bw.w, acc);
    }
    int idx = bb*16 + pix;
    if (c < 4)        dts[pix][kk][c] = acc;
    else if (c < 20)  Bs[(k*L + idx)*16 + (c-4)]  = acc;
    else              Cs[(k*L + idx)*16 + (c-20)] = acc;
  }
  __syncthreads();
  int d = tid & 127, ph = tid >> 7;
  #pragma unroll
  for (int pp = 0; pp < 8; ++pp){
    int pix = pp*2 + ph;
    int idx = bb*16 + pix;
    #pragma unroll
    for (int kk = 0; kk < 2; ++kk){
      int k = (PASS == 0) ? kk*2 : kk*2 + 1;
      const float4 dw = *((const float4*)(dtw + (k*128 + d)*4));
      float acc = dtb[k*128 + d];
      acc = fmaf(dts[pix][kk][0], dw.x, acc);
      acc = fmaf(dts[pix][kk][1], dw.y, acc);
      acc = fmaf(dts[pix][kk][2], dw.z, acc);
      acc = fmaf(dts[pix][kk][3], dw.w, acc);
      delta_s[(k*L + idx)*128 + d] = softplusf(acc);
    }
    u_out[idx*128 + d] = us[pix][d];
  }
}

// -------- K7: scan pass 1 — per-chunk (prod a, local h), n-split -----------
// Block 256 = (d 128) x (nh 2); each thread 8 states. Grid 4*NCH.
__global__ __launch_bounds__(256) void k_scan1(
    const float* __restrict__ delta_s, const float* __restrict__ u_row,
    const float* __restrict__ u_col, const float* __restrict__ Bs,
    const float* __restrict__ Alog, float* __restrict__ P, float* __restrict__ S)
{
  int blk = blockIdx.x;          // k*NCH + chunk
  int k = blk >> 7, ch = blk & (NCH-1);
  int tid = threadIdx.x;
  int d = tid & 127, nh = tid >> 7;
  const float* u_s = (k & 1) ? u_col : u_row;
  float A[8], Pv[8], Sv[8];
  #pragma unroll
  for (int j = 0; j < 8; ++j){
    A[j] = -__expf(Alog[(k*128 + d)*16 + nh*8 + j]);
    Pv[j] = 1.f; Sv[j] = 0.f;
  }
  int base = ch*CT;
  for (int t = 0; t < CT; ++t){
    int tl = base + t;
    int pos = (k < 2) ? tl : (L-1 - tl);
    float dl = delta_s[(k*L + pos)*128 + d];
    float du = dl * u_s[pos*128 + d];
    const float* Br = Bs + (k*L + pos)*16 + nh*8;
    #pragma unroll
    for (int j = 0; j < 8; ++j){
      float a = __expf(dl * A[j]);
      Sv[j] = fmaf(Sv[j], a, du * Br[j]);
      Pv[j] *= a;
    }
  }
  #pragma unroll
  for (int j = 0; j < 8; ++j){
    int o = (blk*16 + nh*8 + j)*128 + d;
    P[o] = Pv[j]; S[o] = Sv[j];
  }
}

// ---------------- K8: scan pass 2 — sequential over NCH chunks -------------
__global__ __launch_bounds__(256) void k_scan2(
    const float* __restrict__ P, const float* __restrict__ S, float* __restrict__ hst)
{
  int g = blockIdx.x * 256 + threadIdx.x;   // 8192 threads: k*2048 + n*128 + d
  int d = g & 127, n = (g >> 7) & 15, k = g >> 11;
  float h = 0.f;
  for (int c = 0; c < NCH; ++c){
    int o = (((k*NCH + c)*16) + n)*128 + d;
    hst[o] = h;
    h = fmaf(P[o], h, S[o]);
  }
}

// -------- K9: scan pass 3 — outputs, lane-pair n-split + shfl reduce -------
// Block 256: lane pair (2t,2t+1) = (d = tid>>1, nh = tid&1), 8 states each.
// Partial y summed via shfl_xor(y,1). Grid 4*NCH.
__global__ __launch_bounds__(256) void k_scan3(
    const float* __restrict__ delta_s, const float* __restrict__ u_row,
    const float* __restrict__ u_col, const float* __restrict__ Bs,
    const float* __restrict__ Cs, const float* __restrict__ Alog,
    const float* __restrict__ hst, float* __restrict__ ys)
{
  int blk = blockIdx.x;
  int k = blk >> 7, ch = blk & (NCH-1);
  int tid = threadIdx.x;
  int d = tid >> 1, nh = tid & 1;
  const float* u_s = (k & 1) ? u_col : u_row;
  float A[8], h[8];
  #pragma unroll
  for (int j = 0; j < 8; ++j){
    A[j] = -__expf(Alog[(k*128 + d)*16 + nh*8 + j]);
    h[j] = hst[(blk*16 + nh*8 + j)*128 + d];
  }
  int base = ch*CT;
  for (int t = 0; t < CT; ++t){
    int tl = base + t;
    int pos = (k < 2) ? tl : (L-1 - tl);
    float dl = delta_s[(k*L + pos)*128 + d];
    float du = dl * u_s[pos*128 + d];
    const float* Br = Bs + (k*L + pos)*16 + nh*8;
    const float* Cr = Cs + (k*L + pos)*16 + nh*8;
    float y = 0.f;
    #pragma unroll
    for (int j = 0; j < 8; ++j){
      float a = __expf(dl * A[j]);
      h[j] = fmaf(h[j], a, du * Br[j]);
      y = fmaf(h[j], Cr[j], y);
    }
    y += __shfl_xor(y, 1);
    if (nh == 0) ys[(k*L + pos)*128 + d] = y;
  }
}

// ------- K10: combine 4 dirs + u*sumD + LN(128) + gate + out_proj + add ----
__global__ __launch_bounds__(128) void k_combine(
    const float* __restrict__ ys, const float* __restrict__ u_row,
    const float* __restrict__ Ds, const float* __restrict__ on_g,
    const float* __restrict__ on_b, const float* __restrict__ sz,
    const float* __restrict__ out_w, const float* __restrict__ ynorm,
    float* __restrict__ yp2)
{
  __shared__ float gs[128];
  __shared__ float rbuf[2][2];
  int p = blockIdx.x;
  int d = threadIdx.x;
  int h = p >> 7, w = p & 127;
  int pT = w*128 + h;
  float y = ys[(0*L + p )*128 + d] + ys[(2*L + p )*128 + d]
          + ys[(1*L + pT)*128 + d] + ys[(3*L + pT)*128 + d];
  float sumD = Ds[d] + Ds[128 + d] + Ds[256 + d] + Ds[384 + d];
  y = fmaf(u_row[p*128 + d], sumD, y);
  float s = wave_sum(y);
  float sq = wave_sum(y*y);
  if ((d & 63) == 0){ rbuf[d>>6][0] = s; rbuf[d>>6][1] = sq; }
  __syncthreads();
  float ts = rbuf[0][0] + rbuf[1][0];
  float tq = rbuf[0][1] + rbuf[1][1];
  float m = ts * (1.f/128.f);
  float va = tq * (1.f/128.f) - m*m;
  float yn = (y - m) * rsqrtf(va + 1e-5f) * on_g[d] + on_b[d];
  gs[d] = yn * sz[p*128 + d];
  __syncthreads();
  if (d < 64){
    const float4* wr = (const float4*)(out_w + d*128);
    const float4* gr = (const float4*)gs;
    float acc = 0.f;
    #pragma unroll
    for (int i = 0; i < 32; ++i){
      float4 a = gr[i], bw = wr[i];
      acc = fmaf(a.x, bw.x, acc); acc = fmaf(a.y, bw.y, acc);
      acc = fmaf(a.z, bw.z, acc); acc = fmaf(a.w, bw.w, acc);
    }
    yp2[p*64 + d] = ynorm[p*64 + d] + acc;
  }
}

// ---------------- K11: depthwise 3x3 (64ch, NHWC) + bias -------------------
__global__ __launch_bounds__(256) void k_dw2a(
    const float* __restrict__ yp2, const float* __restrict__ w,
    const float* __restrict__ b, float* __restrict__ t2)
{
  int g = blockIdx.x * 256 + threadIdx.x;   // 64 * 16384
  int c = g & 63;
  int p = g >> 6;
  int h = p >> 7, ww = p & 127;
  const float* wp = w + c*9;
  float acc = b[c];
  #pragma unroll
  for (int ky = 0; ky < 3; ++ky){
    int hh = h + ky - 1;
    if ((unsigned)hh < 128u){
      #pragma unroll
      for (int kx = 0; kx < 3; ++kx){
        int wx = ww + kx - 1;
        if ((unsigned)wx < 128u)
          acc = fmaf(yp2[(hh*128 + wx)*64 + c], wp[ky*3+kx], acc);
      }
    }
  }
  t2[p*64 + c] = acc;
}

// ---------------- K12: 1x1 64->64 + bias + relu + residual -----------------
__global__ __launch_bounds__(256) void k_dw2b(
    const float* __restrict__ t2, const float* __restrict__ w,
    const float* __restrict__ b, const float* __restrict__ x,
    float* __restrict__ out)
{
  __shared__ float s[16][65];
  int p0 = blockIdx.x * 16;
  for (int i = threadIdx.x; i < 1024; i += 256){
    int pix = i >> 6, c = i & 63;
    s[pix][c] = t2[(p0 + pix)*64 + c];
  }
  __syncthreads();
  int dp = threadIdx.x & 15, cg = threadIdx.x >> 4;
  #pragma unroll
  for (int cc = 0; cc < 4; ++cc){
    int c = cg + cc*16;
    float acc = b[c];
    const float* wp = w + c*64;
    #pragma unroll 8
    for (int i = 0; i < 64; ++i) acc = fmaf(s[dp][i], wp[i], acc);
    acc = fmaxf(acc, 0.f);
    int p = p0 + dp;
    out[c*L + p] = acc + x[c*L + p];
  }
}

extern "C" void kernel_launch(void* const* d_in, const int* in_sizes, int n_in,
                              void* d_out, int out_size, void* d_ws, size_t ws_size,
                              hipStream_t stream)
{
  const float* x       = (const float*)d_in[0];
  const float* conv1_w = (const float*)d_in[1];
  const float* conv1_b = (const float*)d_in[2];
  const float* conv2_w = (const float*)d_in[3];
  const float* conv2_b = (const float*)d_in[4];
  const float* dw1a_w  = (const float*)d_in[5];
  const float* dw1a_b  = (const float*)d_in[6];
  const float* dw1b_w  = (const float*)d_in[7];
  const float* dw1b_b  = (const float*)d_in[8];
  const float* dw2a_w  = (const float*)d_in[9];
  const float* dw2a_b  = (const float*)d_in[10];
  const float* dw2b_w  = (const float*)d_in[11];
  const float* dw2b_b  = (const float*)d_in[12];
  const float* ln_g    = (const float*)d_in[13];
  const float* ln_b    = (const float*)d_in[14];
  const float* ipw     = (const float*)d_in[15];
  const float* cdw_w   = (const float*)d_in[16];
  const float* cdw_b   = (const float*)d_in[17];
  const float* xw      = (const float*)d_in[18];
  const float* dtw     = (const float*)d_in[19];
  const float* dtb     = (const float*)d_in[20];
  const float* Alog    = (const float*)d_in[21];
  const float* DsArr   = (const float*)d_in[22];
  const float* on_g    = (const float*)d_in[23];
  const float* on_b    = (const float*)d_in[24];
  const float* out_w   = (const float*)d_in[25];
  float* out = (float*)d_out;

  char* ws = (char*)d_ws;
  const size_t MB = 1048576ull;
  float* y1      = (float*)(ws + 0*MB);    // 8MB   conv -> K2
  float* t1      = (float*)(ws + 8*MB);    // 8MB   K2 -> K3
  float* y2      = (float*)(ws + 16*MB);   // 4MB   K3 -> K4
  float* xa_pre  = (float*)(ws + 20*MB);   // 8MB   K4 -> K5
  float* wT1     = (float*)(ws + 28*MB);           // 144KB  prep -> conv
  float* wT2     = (float*)(ws + 28*MB + 524288);  // 400KB  prep -> conv
  float* ipwT    = (float*)(ws + 29*MB);           // 64KB   prep -> K4
  float* red     = (float*)(ws + 30*MB);           // 8B     K3 -> K4
  float* ysb     = (float*)(ws + 0*MB);    // 32MB  K9 -> K10 (reuses 0-32, all dead)
  float* delta_s = (float*)(ws + 32*MB);   // 32MB  K6 -> K7/K9
  float* ynorm   = (float*)(ws + 64*MB);   // 4MB   K4 -> K10
  float* sz      = (float*)(ws + 68*MB);   // 8MB   K4 -> K10
  float* u       = (float*)(ws + 76*MB);   // 8MB   K5 -> K6
  float* u_row   = (float*)(ws + 84*MB);   // 8MB   K6 -> K7/K9/K10
  float* u_col   = (float*)(ws + 92*MB);   // 8MB   K6 -> K7/K9
  float* Bsb     = (float*)(ws + 100*MB);  // 4MB   K6 -> K7/K9
  float* Csb     = (float*)(ws + 104*MB);  // 4MB   K6 -> K9
  float* Pb      = (float*)(ws + 108*MB);  // 4MB   K7 -> K8   (NCH=128)
  float* Sb      = (float*)(ws + 112*MB);  // 4MB   K7 -> K8
  float* hst     = (float*)(ws + 116*MB);  // 4MB   K8 -> K9
  float* yp2     = (float*)(ws + 108*MB);  // 4MB   K10 -> K11 (reuses Pb, dead)
  float* t2      = (float*)(ws + 112*MB);  // 4MB   K11 -> K12 (reuses Sb, dead)

  hipMemsetAsync(red, 0, 2*sizeof(float), stream);

  k_prep    <<<608, 256, 0, stream>>>(conv1_w, conv2_w, ipw, wT1, wT2, ipwT);
  k_convC<3><<<512, 256, 0, stream>>>(x, wT1, conv1_b, y1);
  k_convC<5><<<512, 256, 0, stream>>>(x, wT2, conv2_b, y1 + 64*L);
  k_dw1a  <<<8192, 256, 0, stream>>>(y1, dw1a_w, dw1a_b, t1);
  k_dw1b  <<<1024, 256, 0, stream>>>(t1, dw1b_w, dw1b_b, y2, red);
  k_norm_inproj<<<512, 256, 0, stream>>>(y2, red, ln_g, ln_b, ipwT, ynorm, xa_pre, sz);
  k_dwc   <<<8192, 256, 0, stream>>>(xa_pre, cdw_w, cdw_b, u);
  k_proj<0><<<1024, 256, 0, stream>>>(u, xw, dtw, dtb, delta_s, Bsb, Csb, u_row);
  k_proj<1><<<1024, 256, 0, stream>>>(u, xw, dtw, dtb, delta_s, Bsb, Csb, u_col);
  k_scan1 <<<4*NCH, 256, 0, stream>>>(delta_s, u_row, u_col, Bsb, Alog, Pb, Sb);
  k_scan2 <<<32, 256, 0, stream>>>(Pb, Sb, hst);
  k_scan3 <<<4*NCH, 256, 0, stream>>>(delta_s, u_row, u_col, Bsb, Csb, Alog, hst, ysb);
  k_combine<<<16384, 128, 0, stream>>>(ysb, u_row, DsArr, on_g, on_b, sz, out_w, ynorm, yp2);
  k_dw2a  <<<4096, 256, 0, stream>>>(yp2, dw2a_w, dw2a_b, t2);
  k_dw2b  <<<1024, 256, 0, stream>>>(t2, dw2b_w, dw2b_b, x, out);
}

// Round 9
// 636.360 us; speedup vs baseline: 2.0920x; 1.1718x over previous
//
#include <hip/hip_runtime.h>

#define L 16384
#define NCH 128   // scan chunks per direction
#define CT  128   // chunk length (L/NCH)
#define PH 132    // padded rows (pad 2 each side)
#define PW 136    // padded row stride (132 cols + align)

__device__ __forceinline__ float softplusf(float x){
  return (x > 20.f) ? x : log1pf(__expf(x));
}
__device__ __forceinline__ float siluf(float x){
  return x / (1.f + __expf(-x));
}
__device__ __forceinline__ float wave_sum(float v){
  #pragma unroll
  for (int o = 32; o; o >>= 1) v += __shfl_xor(v, o);
  return v;
}

// ---------------- K0: prep — weight transposes ------------------------------
__global__ __launch_bounds__(256) void k_prep(
    const float* __restrict__ w1, const float* __restrict__ w2,
    const float* __restrict__ ipw,
    float* __restrict__ wT1, float* __restrict__ wT2, float* __restrict__ ipwT)
{
  int g = blockIdx.x * 256 + threadIdx.x;
  if (g < 36864){                       // 64*64*9
    int ci = g / 576, rem = g % 576, co = rem / 9, tap = rem % 9;
    wT1[g] = w1[(co*64 + ci)*9 + tap];
  } else if (g < 36864 + 102400){       // 64*64*25
    int g2 = g - 36864;
    int ci = g2 / 1600, rem = g2 % 1600, co = rem / 25, tap = rem % 25;
    wT2[g2] = w2[(co*64 + ci)*25 + tap];
  } else if (g < 36864 + 102400 + 16384){
    int g3 = g - 139264;
    int e = g3 & 255, c = g3 >> 8;
    ipwT[g3] = ipw[e*64 + c];
  }
}

// ---------------- K0b: zero-pad x into [64][PH][PW] -------------------------
__global__ __launch_bounds__(256) void k_pad(
    const float* __restrict__ x, float* __restrict__ xpad)
{
  int g = blockIdx.x * 256 + threadIdx.x;   // 64*PH*PW = 1,148,928
  int ci = g / (PH*PW);
  int r  = (g / PW) % PH;
  int c  = g % PW;
  float v = 0.f;
  int ur = r - 2, uc = c - 2;
  if ((unsigned)ur < 128u && (unsigned)uc < 128u)
    v = x[ci*L + ur*128 + uc];
  xpad[g] = v;
}

// ---------------- K1: dense conv 64->64 split-K, padded input ---------------
// Thread: 2 rows x 4 co, 16 input channels (slice s). No bounds logic.
// Grid 2048 = 16 cg x 32 rq x 4 s -> 8 waves/SIMD. Partials to part[s][co][p].
template<int KS>
__global__ __launch_bounds__(256) void k_convD(
    const float* __restrict__ xpad, const float* __restrict__ wT,
    float* __restrict__ part)
{
  constexpr int P = KS/2, NT = KS*KS;
  const int tid = threadIdx.x;
  const int col = tid & 127;
  const int rh  = tid >> 7;
  const int b   = blockIdx.x;
  const int cg  = b & 15;
  const int rq  = (b >> 4) & 31;
  const int s   = b >> 9;
  const int r0  = rq*4 + rh*2;
  const int co0 = cg*4;
  float acc[2][4];
  #pragma unroll
  for (int q = 0; q < 2; ++q)
    #pragma unroll
    for (int a = 0; a < 4; ++a) acc[q][a] = 0.f;

  const int ci0 = s*16;
  for (int ci = ci0; ci < ci0+16; ++ci){
    const float* xb = xpad + ci*(PH*PW) + (r0 - P + 2)*PW + (col - P + 2);
    const float* wp = wT + (ci*64 + co0)*NT;
    #pragma unroll
    for (int ir = 0; ir < KS+1; ++ir){
      float xrow[KS];
      #pragma unroll
      for (int kx = 0; kx < KS; ++kx) xrow[kx] = xb[ir*PW + kx];
      #pragma unroll
      for (int q = 0; q < 2; ++q){
        int ky = ir - q;
        if (ky >= 0 && ky < KS){
          #pragma unroll
          for (int kx = 0; kx < KS; ++kx){
            #pragma unroll
            for (int a = 0; a < 4; ++a)
              acc[q][a] = fmaf(xrow[kx], wp[a*NT + ky*KS + kx], acc[q][a]);
          }
        }
      }
    }
  }
  #pragma unroll
  for (int q = 0; q < 2; ++q){
    const int p = (r0+q)*128 + col;
    #pragma unroll
    for (int a = 0; a < 4; ++a)
      part[(s*64 + co0+a)*L + p] = acc[q][a];
  }
}

// ---------------- K1c: reduce 4 slices + bias + relu -> y1 (128ch) ---------
__global__ __launch_bounds__(256) void k_convred(
    const float* __restrict__ part1, const float* __restrict__ part2,
    const float* __restrict__ b1, const float* __restrict__ b2,
    float* __restrict__ y1)
{
  int g = blockIdx.x * 256 + threadIdx.x;   // 128 * 16384
  int ch = g >> 14, p = g & (L-1);
  float v;
  if (ch < 64){
    v = b1[ch];
    #pragma unroll
    for (int s = 0; s < 4; ++s) v += part1[(s*64 + ch)*L + p];
  } else {
    int c = ch - 64;
    v = b2[c];
    #pragma unroll
    for (int s = 0; s < 4; ++s) v += part2[(s*64 + c)*L + p];
  }
  y1[ch*L + p] = fmaxf(v, 0.f);
}

// ---------------- K2: grouped conv dw1a (128ch, groups=64, 2in/2out, 3x3) ---
__global__ __launch_bounds__(256) void k_dw1a(
    const float* __restrict__ y1, const float* __restrict__ w, const float* __restrict__ b,
    float* __restrict__ t1)
{
  int g = blockIdx.x * 256 + threadIdx.x;      // 128 * 16384 threads
  int p = g & (L-1);
  int o = g >> 14;
  int h = p >> 7, ww = p & 127;
  int grp = o >> 1;
  float acc = b[o];
  #pragma unroll
  for (int i = 0; i < 2; ++i){
    const float* xp = y1 + (grp*2 + i)*L;
    const float* wp = w + (o*2 + i)*9;
    #pragma unroll
    for (int ky = 0; ky < 3; ++ky){
      int hh = h + ky - 1;
      if ((unsigned)hh < 128u){
        #pragma unroll
        for (int kx = 0; kx < 3; ++kx){
          int wx = ww + kx - 1;
          if ((unsigned)wx < 128u)
            acc = fmaf(xp[hh*128 + wx], wp[ky*3+kx], acc);
        }
      }
    }
  }
  t1[o*L + p] = acc;
}

// ---------------- K3: 1x1 conv 128->64 + bias + relu + global sum/sumsq ----
__global__ __launch_bounds__(256) void k_dw1b(
    const float* __restrict__ t1, const float* __restrict__ w, const float* __restrict__ b,
    float* __restrict__ y2, float* __restrict__ red)
{
  __shared__ float s[16][130];
  __shared__ float rs[4][2];
  int p0 = blockIdx.x * 16;
  for (int i = threadIdx.x; i < 2048; i += 256){
    int ci = i >> 4, dp = i & 15;
    s[dp][ci] = t1[ci*L + p0 + dp];
  }
  __syncthreads();
  int dp = threadIdx.x & 15, cg = threadIdx.x >> 4;
  float lsum = 0.f, lsq = 0.f;
  #pragma unroll
  for (int cc = 0; cc < 4; ++cc){
    int c = cg + cc*16;
    float acc = b[c];
    const float* wp = w + c*128;
    #pragma unroll 8
    for (int i = 0; i < 128; ++i) acc = fmaf(s[dp][i], wp[i], acc);
    acc = fmaxf(acc, 0.f);
    y2[c*L + p0 + dp] = acc;
    lsum += acc; lsq += acc*acc;
  }
  lsum = wave_sum(lsum); lsq = wave_sum(lsq);
  if ((threadIdx.x & 63) == 0){ rs[threadIdx.x>>6][0] = lsum; rs[threadIdx.x>>6][1] = lsq; }
  __syncthreads();
  if (threadIdx.x == 0){
    float a = rs[0][0]+rs[1][0]+rs[2][0]+rs[3][0];
    float q = rs[0][1]+rs[1][1]+rs[2][1]+rs[3][1];
    atomicAdd(&red[0], a);
    atomicAdd(&red[1], q);
  }
}

// ------- K4: global norm + LN(64) + in_proj (64->256), LDS-staged weights --
__global__ __launch_bounds__(256) void k_norm_inproj(
    const float* __restrict__ y2, const float* __restrict__ red,
    const float* __restrict__ ln_g, const float* __restrict__ ln_b,
    const float* __restrict__ ipwT,
    float* __restrict__ ynorm, float* __restrict__ xa_pre, float* __restrict__ sz)
{
  __shared__ float ws_s[16384];     // [c][e] 64x256
  __shared__ float ls_s[64*33];     // [c][pix] stride 33
  __shared__ float mv_s[2][32];
  const int tid = threadIdx.x;
  const int p0 = blockIdx.x * 32;
  {
    const float4* src = (const float4*)ipwT;
    float4* dst = (float4*)ws_s;
    #pragma unroll
    for (int i = 0; i < 16; ++i) dst[tid + i*256] = src[tid + i*256];
  }
  const float invN = 1.f / 1048576.f;
  float mu = red[0] * invN;
  float var = red[1] * invN - mu*mu;
  float rsg = rsqrtf(var + 1e-5f);
  for (int i = tid; i < 2048; i += 256){
    int c = i >> 5, pix = i & 31;
    ls_s[c*33 + pix] = (y2[c*L + p0 + pix] - mu) * rsg;
  }
  __syncthreads();
  for (int i = tid; i < 2048; i += 256){
    int pix = i >> 6, c = i & 63;
    ynorm[(p0 + pix)*64 + c] = ls_s[c*33 + pix];
  }
  if (tid < 32){
    float s = 0.f, q = 0.f;
    #pragma unroll 8
    for (int c = 0; c < 64; ++c){
      float v = ls_s[c*33 + tid];
      s += v; q += v*v;
    }
    float m = s * (1.f/64.f);
    float va = q * (1.f/64.f) - m*m;
    mv_s[0][tid] = m;
    mv_s[1][tid] = rsqrtf(va + 1e-5f);
  }
  __syncthreads();
  for (int i = tid; i < 2048; i += 256){
    int c = i >> 5, pix = i & 31;
    float v = ls_s[c*33 + pix];
    ls_s[c*33 + pix] = (v - mv_s[0][pix]) * mv_s[1][pix] * ln_g[c] + ln_b[c];
  }
  __syncthreads();
  const int pix = tid & 31, eh = tid >> 5;
  float acc[32];
  #pragma unroll
  for (int j = 0; j < 32; ++j) acc[j] = 0.f;
  for (int c = 0; c < 64; ++c){
    float lnv = ls_s[c*33 + pix];
    const float4* w4 = (const float4*)(ws_s + c*256 + eh*32);
    #pragma unroll
    for (int j = 0; j < 8; ++j){
      float4 wq = w4[j];
      acc[j*4+0] = fmaf(lnv, wq.x, acc[j*4+0]);
      acc[j*4+1] = fmaf(lnv, wq.y, acc[j*4+1]);
      acc[j*4+2] = fmaf(lnv, wq.z, acc[j*4+2]);
      acc[j*4+3] = fmaf(lnv, wq.w, acc[j*4+3]);
    }
  }
  __syncthreads();
  float* szs = ws_s; // [pix][129]
  const int p = p0 + pix;
  if (eh < 4){
    const int e0 = eh*32;
    #pragma unroll
    for (int j = 0; j < 32; ++j)
      xa_pre[(e0+j)*L + p] = acc[j];
  } else {
    const int j0 = (eh-4)*32;
    #pragma unroll
    for (int j = 0; j < 32; ++j)
      szs[pix*129 + j0 + j] = siluf(acc[j]);
  }
  __syncthreads();
  for (int i = tid; i < 32*128; i += 256){
    int pix2 = i >> 7, j = i & 127;
    sz[(p0 + pix2)*128 + j] = szs[pix2*129 + j];
  }
}

// ---------------- K5: depthwise 3x3 (128ch) + bias + silu ------------------
__global__ __launch_bounds__(256) void k_dwc(
    const float* __restrict__ xa, const float* __restrict__ w, const float* __restrict__ b,
    float* __restrict__ u)
{
  int g = blockIdx.x * 256 + threadIdx.x;
  int p = g & (L-1);
  int d = g >> 14;
  int h = p >> 7, ww = p & 127;
  const float* xp = xa + d*L;
  const float* wp = w + d*9;
  float acc = b[d];
  #pragma unroll
  for (int ky = 0; ky < 3; ++ky){
    int hh = h + ky - 1;
    if ((unsigned)hh < 128u){
      #pragma unroll
      for (int kx = 0; kx < 3; ++kx){
        int wx = ww + kx - 1;
        if ((unsigned)wx < 128u)
          acc = fmaf(xp[hh*128 + wx], wp[ky*3+kx], acc);
      }
    }
  }
  u[d*L + p] = siluf(acc);
}

// ------- K6: per-pixel x_proj (128->36) + delta softplus, scan-order store -
template<int PASS>  // PASS 0: k={0,2}, row-major idx=p ; PASS 1: k={1,3}, idx = w*128+h
__global__ __launch_bounds__(256) void k_proj(
    const float* __restrict__ u, const float* __restrict__ xw,
    const float* __restrict__ dtw, const float* __restrict__ dtb,
    float* __restrict__ delta_s, float* __restrict__ Bs, float* __restrict__ Cs,
    float* __restrict__ u_out)
{
  __shared__ float us[16][132];
  __shared__ float dts[16][2][4];
  int bb = blockIdx.x;
  int tid = threadIdx.x;
  for (int i = tid; i < 16*128; i += 256){
    int d = i >> 4, pix = i & 15;
    int idx = bb*16 + pix;
    int p;
    if (PASS == 0) p = idx;
    else           p = (idx & 127)*128 + (idx >> 7);
    us[pix][d] = u[d*L + p];
  }
  __syncthreads();
  for (int o = tid; o < 1152; o += 256){
    int pix = o / 72; int r = o % 72; int kk = r / 36; int c = r % 36;
    int k = (PASS == 0) ? kk*2 : kk*2 + 1;
    const float4* ur = (const float4*)(&us[pix][0]);
    const float4* wr = (const float4*)(xw + (k*36 + c)*128);
    float acc = 0.f;
    #pragma unroll
    for (int i = 0; i < 32; ++i){
      float4 a = ur[i], bw = wr[i];
      acc = fmaf(a.x, bw.x, acc); acc = fmaf(a.y, bw.y, acc);
      acc = fmaf(a.z, bw.z, acc); acc = fmaf(a.w, bw.w, acc);
    }
    int idx = bb*16 + pix;
    if (c < 4)        dts[pix][kk][c] = acc;
    else if (c < 20)  Bs[(k*L + idx)*16 + (c-4)]  = acc;
    else              Cs[(k*L + idx)*16 + (c-20)] = acc;
  }
  __syncthreads();
  int d = tid & 127, ph = tid >> 7;
  #pragma unroll
  for (int pp = 0; pp < 8; ++pp){
    int pix = pp*2 + ph;
    int idx = bb*16 + pix;
    #pragma unroll
    for (int kk = 0; kk < 2; ++kk){
      int k = (PASS == 0) ? kk*2 : kk*2 + 1;
      const float4 dw = *((const float4*)(dtw + (k*128 + d)*4));
      float acc = dtb[k*128 + d];
      acc = fmaf(dts[pix][kk][0], dw.x, acc);
      acc = fmaf(dts[pix][kk][1], dw.y, acc);
      acc = fmaf(dts[pix][kk][2], dw.z, acc);
      acc = fmaf(dts[pix][kk][3], dw.w, acc);
      delta_s[(k*L + idx)*128 + d] = softplusf(acc);
    }
    u_out[idx*128 + d] = us[pix][d];
  }
}

// -------- K7: scan pass 1 — per-chunk (prod a, local h), n-split -----------
__global__ __launch_bounds__(256) void k_scan1(
    const float* __restrict__ delta_s, const float* __restrict__ u_row,
    const float* __restrict__ u_col, const float* __restrict__ Bs,
    const float* __restrict__ Alog, float* __restrict__ P, float* __restrict__ S)
{
  int blk = blockIdx.x;          // k*NCH + chunk
  int k = blk >> 7, ch = blk & (NCH-1);
  int tid = threadIdx.x;
  int d = tid & 127, nh = tid >> 7;
  const float* u_s = (k & 1) ? u_col : u_row;
  float A[8], Pv[8], Sv[8];
  #pragma unroll
  for (int j = 0; j < 8; ++j){
    A[j] = -__expf(Alog[(k*128 + d)*16 + nh*8 + j]);
    Pv[j] = 1.f; Sv[j] = 0.f;
  }
  int base = ch*CT;
  for (int t = 0; t < CT; ++t){
    int tl = base + t;
    int pos = (k < 2) ? tl : (L-1 - tl);
    float dl = delta_s[(k*L + pos)*128 + d];
    float du = dl * u_s[pos*128 + d];
    const float* Br = Bs + (k*L + pos)*16 + nh*8;
    #pragma unroll
    for (int j = 0; j < 8; ++j){
      float a = __expf(dl * A[j]);
      Sv[j] = fmaf(Sv[j], a, du * Br[j]);
      Pv[j] *= a;
    }
  }
  #pragma unroll
  for (int j = 0; j < 8; ++j){
    int o = (blk*16 + nh*8 + j)*128 + d;
    P[o] = Pv[j]; S[o] = Sv[j];
  }
}

// ---------------- K8: scan pass 2 — sequential over NCH chunks -------------
__global__ __launch_bounds__(256) void k_scan2(
    const float* __restrict__ P, const float* __restrict__ S, float* __restrict__ hst)
{
  int g = blockIdx.x * 256 + threadIdx.x;   // 8192 threads: k*2048 + n*128 + d
  int d = g & 127, n = (g >> 7) & 15, k = g >> 11;
  float h = 0.f;
  for (int c = 0; c < NCH; ++c){
    int o = (((k*NCH + c)*16) + n)*128 + d;
    hst[o] = h;
    h = fmaf(P[o], h, S[o]);
  }
}

// -------- K9: scan pass 3 — outputs, lane-pair n-split + shfl reduce -------
__global__ __launch_bounds__(256) void k_scan3(
    const float* __restrict__ delta_s, const float* __restrict__ u_row,
    const float* __restrict__ u_col, const float* __restrict__ Bs,
    const float* __restrict__ Cs, const float* __restrict__ Alog,
    const float* __restrict__ hst, float* __restrict__ ys)
{
  int blk = blockIdx.x;
  int k = blk >> 7, ch = blk & (NCH-1);
  int tid = threadIdx.x;
  int d = tid >> 1, nh = tid & 1;
  const float* u_s = (k & 1) ? u_col : u_row;
  float A[8], h[8];
  #pragma unroll
  for (int j = 0; j < 8; ++j){
    A[j] = -__expf(Alog[(k*128 + d)*16 + nh*8 + j]);
    h[j] = hst[(blk*16 + nh*8 + j)*128 + d];
  }
  int base = ch*CT;
  for (int t = 0; t < CT; ++t){
    int tl = base + t;
    int pos = (k < 2) ? tl : (L-1 - tl);
    float dl = delta_s[(k*L + pos)*128 + d];
    float du = dl * u_s[pos*128 + d];
    const float* Br = Bs + (k*L + pos)*16 + nh*8;
    const float* Cr = Cs + (k*L + pos)*16 + nh*8;
    float y = 0.f;
    #pragma unroll
    for (int j = 0; j < 8; ++j){
      float a = __expf(dl * A[j]);
      h[j] = fmaf(h[j], a, du * Br[j]);
      y = fmaf(h[j], Cr[j], y);
    }
    y += __shfl_xor(y, 1);
    if (nh == 0) ys[(k*L + pos)*128 + d] = y;
  }
}

// ------- K10: combine 4 dirs + u*sumD + LN(128) + gate + out_proj + add ----
__global__ __launch_bounds__(128) void k_combine(
    const float* __restrict__ ys, const float* __restrict__ u_row,
    const float* __restrict__ Ds, const float* __restrict__ on_g,
    const float* __restrict__ on_b, const float* __restrict__ sz,
    const float* __restrict__ out_w, const float* __restrict__ ynorm,
    float* __restrict__ yp2)
{
  __shared__ float gs[128];
  __shared__ float rbuf[2][2];
  int p = blockIdx.x;
  int d = threadIdx.x;
  int h = p >> 7, w = p & 127;
  int pT = w*128 + h;
  float y = ys[(0*L + p )*128 + d] + ys[(2*L + p )*128 + d]
          + ys[(1*L + pT)*128 + d] + ys[(3*L + pT)*128 + d];
  float sumD = Ds[d] + Ds[128 + d] + Ds[256 + d] + Ds[384 + d];
  y = fmaf(u_row[p*128 + d], sumD, y);
  float s = wave_sum(y);
  float sq = wave_sum(y*y);
  if ((d & 63) == 0){ rbuf[d>>6][0] = s; rbuf[d>>6][1] = sq; }
  __syncthreads();
  float ts = rbuf[0][0] + rbuf[1][0];
  float tq = rbuf[0][1] + rbuf[1][1];
  float m = ts * (1.f/128.f);
  float va = tq * (1.f/128.f) - m*m;
  float yn = (y - m) * rsqrtf(va + 1e-5f) * on_g[d] + on_b[d];
  gs[d] = yn * sz[p*128 + d];
  __syncthreads();
  if (d < 64){
    const float4* wr = (const float4*)(out_w + d*128);
    const float4* gr = (const float4*)gs;
    float acc = 0.f;
    #pragma unroll
    for (int i = 0; i < 32; ++i){
      float4 a = gr[i], bw = wr[i];
      acc = fmaf(a.x, bw.x, acc); acc = fmaf(a.y, bw.y, acc);
      acc = fmaf(a.z, bw.z, acc); acc = fmaf(a.w, bw.w, acc);
    }
    yp2[p*64 + d] = ynorm[p*64 + d] + acc;
  }
}

// ---------------- K11: depthwise 3x3 (64ch, NHWC) + bias -------------------
__global__ __launch_bounds__(256) void k_dw2a(
    const float* __restrict__ yp2, const float* __restrict__ w,
    const float* __restrict__ b, float* __restrict__ t2)
{
  int g = blockIdx.x * 256 + threadIdx.x;   // 64 * 16384
  int c = g & 63;
  int p = g >> 6;
  int h = p >> 7, ww = p & 127;
  const float* wp = w + c*9;
  float acc = b[c];
  #pragma unroll
  for (int ky = 0; ky < 3; ++ky){
    int hh = h + ky - 1;
    if ((unsigned)hh < 128u){
      #pragma unroll
      for (int kx = 0; kx < 3; ++kx){
        int wx = ww + kx - 1;
        if ((unsigned)wx < 128u)
          acc = fmaf(yp2[(hh*128 + wx)*64 + c], wp[ky*3+kx], acc);
      }
    }
  }
  t2[p*64 + c] = acc;
}

// ---------------- K12: 1x1 64->64 + bias + relu + residual -----------------
__global__ __launch_bounds__(256) void k_dw2b(
    const float* __restrict__ t2, const float* __restrict__ w,
    const float* __restrict__ b, const float* __restrict__ x,
    float* __restrict__ out)
{
  __shared__ float s[16][65];
  int p0 = blockIdx.x * 16;
  for (int i = threadIdx.x; i < 1024; i += 256){
    int pix = i >> 6, c = i & 63;
    s[pix][c] = t2[(p0 + pix)*64 + c];
  }
  __syncthreads();
  int dp = threadIdx.x & 15, cg = threadIdx.x >> 4;
  #pragma unroll
  for (int cc = 0; cc < 4; ++cc){
    int c = cg + cc*16;
    float acc = b[c];
    const float* wp = w + c*64;
    #pragma unroll 8
    for (int i = 0; i < 64; ++i) acc = fmaf(s[dp][i], wp[i], acc);
    acc = fmaxf(acc, 0.f);
    int p = p0 + dp;
    out[c*L + p] = acc + x[c*L + p];
  }
}

extern "C" void kernel_launch(void* const* d_in, const int* in_sizes, int n_in,
                              void* d_out, int out_size, void* d_ws, size_t ws_size,
                              hipStream_t stream)
{
  const float* x       = (const float*)d_in[0];
  const float* conv1_w = (const float*)d_in[1];
  const float* conv1_b = (const float*)d_in[2];
  const float* conv2_w = (const float*)d_in[3];
  const float* conv2_b = (const float*)d_in[4];
  const float* dw1a_w  = (const float*)d_in[5];
  const float* dw1a_b  = (const float*)d_in[6];
  const float* dw1b_w  = (const float*)d_in[7];
  const float* dw1b_b  = (const float*)d_in[8];
  const float* dw2a_w  = (const float*)d_in[9];
  const float* dw2a_b  = (const float*)d_in[10];
  const float* dw2b_w  = (const float*)d_in[11];
  const float* dw2b_b  = (const float*)d_in[12];
  const float* ln_g    = (const float*)d_in[13];
  const float* ln_b    = (const float*)d_in[14];
  const float* ipw     = (const float*)d_in[15];
  const float* cdw_w   = (const float*)d_in[16];
  const float* cdw_b   = (const float*)d_in[17];
  const float* xw      = (const float*)d_in[18];
  const float* dtw     = (const float*)d_in[19];
  const float* dtb     = (const float*)d_in[20];
  const float* Alog    = (const float*)d_in[21];
  const float* DsArr   = (const float*)d_in[22];
  const float* on_g    = (const float*)d_in[23];
  const float* on_b    = (const float*)d_in[24];
  const float* out_w   = (const float*)d_in[25];
  float* out = (float*)d_out;

  char* ws = (char*)d_ws;
  const size_t MB = 1048576ull;
  float* y1      = (float*)(ws + 0*MB);    // 8MB   convred -> K2
  float* t1      = (float*)(ws + 8*MB);    // 8MB   K2 -> K3
  float* y2      = (float*)(ws + 16*MB);   // 4MB   K3 -> K4
  float* xpad    = (float*)(ws + 20*MB);   // 4.6MB pad -> conv (dead after; xa_pre reuses)
  float* xa_pre  = (float*)(ws + 20*MB);   // 8MB   K4 -> K5
  float* wT1     = (float*)(ws + 28*MB);           // 144KB  prep -> conv
  float* wT2     = (float*)(ws + 28*MB + 524288);  // 400KB  prep -> conv
  float* ipwT    = (float*)(ws + 29*MB);           // 64KB   prep -> K4
  float* red     = (float*)(ws + 30*MB);           // 8B     K3 -> K4
  float* part1   = (float*)(ws + 32*MB);   // 16MB  convD3 -> convred (delta_s reuses)
  float* part2   = (float*)(ws + 48*MB);   // 16MB  convD5 -> convred
  float* ysb     = (float*)(ws + 0*MB);    // 32MB  K9 -> K10 (reuses 0-32, all dead)
  float* delta_s = (float*)(ws + 32*MB);   // 32MB  K6 -> K7/K9
  float* ynorm   = (float*)(ws + 64*MB);   // 4MB   K4 -> K10
  float* sz      = (float*)(ws + 68*MB);   // 8MB   K4 -> K10
  float* u       = (float*)(ws + 76*MB);   // 8MB   K5 -> K6
  float* u_row   = (float*)(ws + 84*MB);   // 8MB   K6 -> K7/K9/K10
  float* u_col   = (float*)(ws + 92*MB);   // 8MB   K6 -> K7/K9
  float* Bsb     = (float*)(ws + 100*MB);  // 4MB   K6 -> K7/K9
  float* Csb     = (float*)(ws + 104*MB);  // 4MB   K6 -> K9
  float* Pb      = (float*)(ws + 108*MB);  // 4MB   K7 -> K8   (NCH=128)
  float* Sb      = (float*)(ws + 112*MB);  // 4MB   K7 -> K8
  float* hst     = (float*)(ws + 116*MB);  // 4MB   K8 -> K9
  float* yp2     = (float*)(ws + 108*MB);  // 4MB   K10 -> K11 (reuses Pb, dead)
  float* t2      = (float*)(ws + 112*MB);  // 4MB   K11 -> K12 (reuses Sb, dead)

  hipMemsetAsync(red, 0, 2*sizeof(float), stream);

  k_prep    <<<608, 256, 0, stream>>>(conv1_w, conv2_w, ipw, wT1, wT2, ipwT);
  k_pad     <<<4488, 256, 0, stream>>>(x, xpad);
  k_convD<3><<<2048, 256, 0, stream>>>(xpad, wT1, part1);
  k_convD<5><<<2048, 256, 0, stream>>>(xpad, wT2, part2);
  k_convred <<<8192, 256, 0, stream>>>(part1, part2, conv1_b, conv2_b, y1);
  k_dw1a  <<<8192, 256, 0, stream>>>(y1, dw1a_w, dw1a_b, t1);
  k_dw1b  <<<1024, 256, 0, stream>>>(t1, dw1b_w, dw1b_b, y2, red);
  k_norm_inproj<<<512, 256, 0, stream>>>(y2, red, ln_g, ln_b, ipwT, ynorm, xa_pre, sz);
  k_dwc   <<<8192, 256, 0, stream>>>(xa_pre, cdw_w, cdw_b, u);
  k_proj<0><<<1024, 256, 0, stream>>>(u, xw, dtw, dtb, delta_s, Bsb, Csb, u_row);
  k_proj<1><<<1024, 256, 0, stream>>>(u, xw, dtw, dtb, delta_s, Bsb, Csb, u_col);
  k_scan1 <<<4*NCH, 256, 0, stream>>>(delta_s, u_row, u_col, Bsb, Alog, Pb, Sb);
  k_scan2 <<<32, 256, 0, stream>>>(Pb, Sb, hst);
  k_scan3 <<<4*NCH, 256, 0, stream>>>(delta_s, u_row, u_col, Bsb, Csb, Alog, hst, ysb);
  k_combine<<<16384, 128, 0, stream>>>(ysb, u_row, DsArr, on_g, on_b, sz, out_w, ynorm, yp2);
  k_dw2a  <<<4096, 256, 0, stream>>>(yp2, dw2a_w, dw2a_b, t2);
  k_dw2b  <<<1024, 256, 0, stream>>>(t2, dw2b_w, dw2b_b, x, out);
}

// Round 14
// 607.759 us; speedup vs baseline: 2.1905x; 1.0471x over previous
//
#include <hip/hip_runtime.h>

#define L 16384
#define NCH 128   // scan chunks per direction
#define CT  128   // chunk length (L/NCH)
#define PH 132    // padded rows (pad 2 each side)
#define PW 136    // padded row stride (132 cols + align)

__device__ __forceinline__ float softplusf(float x){
  return (x > 20.f) ? x : log1pf(__expf(x));
}
__device__ __forceinline__ float siluf(float x){
  return x / (1.f + __expf(-x));
}
__device__ __forceinline__ float wave_sum(float v){
  #pragma unroll
  for (int o = 32; o; o >>= 1) v += __shfl_xor(v, o);
  return v;
}

// ---------------- K0: prep — weight transposes ------------------------------
__global__ __launch_bounds__(256) void k_prep(
    const float* __restrict__ w1, const float* __restrict__ w2,
    const float* __restrict__ ipw,
    float* __restrict__ wT1, float* __restrict__ wT2, float* __restrict__ ipwT)
{
  int g = blockIdx.x * 256 + threadIdx.x;
  if (g < 36864){                       // 64*64*9
    int ci = g / 576, rem = g % 576, co = rem / 9, tap = rem % 9;
    wT1[g] = w1[(co*64 + ci)*9 + tap];
  } else if (g < 36864 + 102400){       // 64*64*25
    int g2 = g - 36864;
    int ci = g2 / 1600, rem = g2 % 1600, co = rem / 25, tap = rem % 25;
    wT2[g2] = w2[(co*64 + ci)*25 + tap];
  } else if (g < 36864 + 102400 + 16384){
    int g3 = g - 139264;
    int e = g3 & 255, c = g3 >> 8;
    ipwT[g3] = ipw[e*64 + c];
  }
}

// ---------------- K0b: zero-pad x into [64][PH][PW] -------------------------
__global__ __launch_bounds__(256) void k_pad(
    const float* __restrict__ x, float* __restrict__ xpad)
{
  int g = blockIdx.x * 256 + threadIdx.x;   // 64*PH*PW = 1,148,928
  int ci = g / (PH*PW);
  int r  = (g / PW) % PH;
  int c  = g % PW;
  float v = 0.f;
  int ur = r - 2, uc = c - 2;
  if ((unsigned)ur < 128u && (unsigned)uc < 128u)
    v = x[ci*L + ur*128 + uc];
  xpad[g] = v;
}

// ---------------- K1: dense conv 64->64 split-K, padded input ---------------
template<int KS>
__global__ __launch_bounds__(256) void k_convD(
    const float* __restrict__ xpad, const float* __restrict__ wT,
    float* __restrict__ part)
{
  constexpr int P = KS/2, NT = KS*KS;
  const int tid = threadIdx.x;
  const int col = tid & 127;
  const int rh  = tid >> 7;
  const int b   = blockIdx.x;
  const int cg  = b & 15;
  const int rq  = (b >> 4) & 31;
  const int s   = b >> 9;
  const int r0  = rq*4 + rh*2;
  const int co0 = cg*4;
  float acc[2][4];
  #pragma unroll
  for (int q = 0; q < 2; ++q)
    #pragma unroll
    for (int a = 0; a < 4; ++a) acc[q][a] = 0.f;

  const int ci0 = s*16;
  for (int ci = ci0; ci < ci0+16; ++ci){
    const float* xb = xpad + ci*(PH*PW) + (r0 - P + 2)*PW + (col - P + 2);
    const float* wp = wT + (ci*64 + co0)*NT;
    #pragma unroll
    for (int ir = 0; ir < KS+1; ++ir){
      float xrow[KS];
      #pragma unroll
      for (int kx = 0; kx < KS; ++kx) xrow[kx] = xb[ir*PW + kx];
      #pragma unroll
      for (int q = 0; q < 2; ++q){
        int ky = ir - q;
        if (ky >= 0 && ky < KS){
          #pragma unroll
          for (int kx = 0; kx < KS; ++kx){
            #pragma unroll
            for (int a = 0; a < 4; ++a)
              acc[q][a] = fmaf(xrow[kx], wp[a*NT + ky*KS + kx], acc[q][a]);
          }
        }
      }
    }
  }
  #pragma unroll
  for (int q = 0; q < 2; ++q){
    const int p = (r0+q)*128 + col;
    #pragma unroll
    for (int a = 0; a < 4; ++a)
      part[(s*64 + co0+a)*L + p] = acc[q][a];
  }
}

// ---------------- K1c: reduce 4 slices + bias + relu -> y1 (128ch) ---------
__global__ __launch_bounds__(256) void k_convred(
    const float* __restrict__ part1, const float* __restrict__ part2,
    const float* __restrict__ b1, const float* __restrict__ b2,
    float* __restrict__ y1)
{
  int g = blockIdx.x * 256 + threadIdx.x;   // 128 * 16384
  int ch = g >> 14, p = g & (L-1);
  float v;
  if (ch < 64){
    v = b1[ch];
    #pragma unroll
    for (int s = 0; s < 4; ++s) v += part1[(s*64 + ch)*L + p];
  } else {
    int c = ch - 64;
    v = b2[c];
    #pragma unroll
    for (int s = 0; s < 4; ++s) v += part2[(s*64 + c)*L + p];
  }
  y1[ch*L + p] = fmaxf(v, 0.f);
}

// ---------------- K2: grouped conv dw1a (128ch, groups=64, 2in/2out, 3x3) ---
__global__ __launch_bounds__(256) void k_dw1a(
    const float* __restrict__ y1, const float* __restrict__ w, const float* __restrict__ b,
    float* __restrict__ t1)
{
  int g = blockIdx.x * 256 + threadIdx.x;      // 128 * 16384 threads
  int p = g & (L-1);
  int o = g >> 14;
  int h = p >> 7, ww = p & 127;
  int grp = o >> 1;
  float acc = b[o];
  #pragma unroll
  for (int i = 0; i < 2; ++i){
    const float* xp = y1 + (grp*2 + i)*L;
    const float* wp = w + (o*2 + i)*9;
    #pragma unroll
    for (int ky = 0; ky < 3; ++ky){
      int hh = h + ky - 1;
      if ((unsigned)hh < 128u){
        #pragma unroll
        for (int kx = 0; kx < 3; ++kx){
          int wx = ww + kx - 1;
          if ((unsigned)wx < 128u)
            acc = fmaf(xp[hh*128 + wx], wp[ky*3+kx], acc);
        }
      }
    }
  }
  t1[o*L + p] = acc;
}

// ---------------- K3: 1x1 conv 128->64 + bias + relu + global sum/sumsq ----
__global__ __launch_bounds__(256) void k_dw1b(
    const float* __restrict__ t1, const float* __restrict__ w, const float* __restrict__ b,
    float* __restrict__ y2, float* __restrict__ red)
{
  __shared__ float s[16][130];
  __shared__ float rs[4][2];
  int p0 = blockIdx.x * 16;
  for (int i = threadIdx.x; i < 2048; i += 256){
    int ci = i >> 4, dp = i & 15;
    s[dp][ci] = t1[ci*L + p0 + dp];
  }
  __syncthreads();
  int dp = threadIdx.x & 15, cg = threadIdx.x >> 4;
  float lsum = 0.f, lsq = 0.f;
  #pragma unroll
  for (int cc = 0; cc < 4; ++cc){
    int c = cg + cc*16;
    float acc = b[c];
    const float* wp = w + c*128;
    #pragma unroll 8
    for (int i = 0; i < 128; ++i) acc = fmaf(s[dp][i], wp[i], acc);
    acc = fmaxf(acc, 0.f);
    y2[c*L + p0 + dp] = acc;
    lsum += acc; lsq += acc*acc;
  }
  lsum = wave_sum(lsum); lsq = wave_sum(lsq);
  if ((threadIdx.x & 63) == 0){ rs[threadIdx.x>>6][0] = lsum; rs[threadIdx.x>>6][1] = lsq; }
  __syncthreads();
  if (threadIdx.x == 0){
    float a = rs[0][0]+rs[1][0]+rs[2][0]+rs[3][0];
    float q = rs[0][1]+rs[1][1]+rs[2][1]+rs[3][1];
    atomicAdd(&red[0], a);
    atomicAdd(&red[1], q);
  }
}

// ------- K4: global norm + LN(64) + in_proj (64->256), LDS-staged weights --
__global__ __launch_bounds__(256) void k_norm_inproj(
    const float* __restrict__ y2, const float* __restrict__ red,
    const float* __restrict__ ln_g, const float* __restrict__ ln_b,
    const float* __restrict__ ipwT,
    float* __restrict__ ynorm, float* __restrict__ xa_pre, float* __restrict__ sz)
{
  __shared__ float ws_s[16384];     // [c][e] 64x256
  __shared__ float ls_s[64*33];     // [c][pix] stride 33
  __shared__ float mv_s[2][32];
  const int tid = threadIdx.x;
  const int p0 = blockIdx.x * 32;
  {
    const float4* src = (const float4*)ipwT;
    float4* dst = (float4*)ws_s;
    #pragma unroll
    for (int i = 0; i < 16; ++i) dst[tid + i*256] = src[tid + i*256];
  }
  const float invN = 1.f / 1048576.f;
  float mu = red[0] * invN;
  float var = red[1] * invN - mu*mu;
  float rsg = rsqrtf(var + 1e-5f);
  for (int i = tid; i < 2048; i += 256){
    int c = i >> 5, pix = i & 31;
    ls_s[c*33 + pix] = (y2[c*L + p0 + pix] - mu) * rsg;
  }
  __syncthreads();
  for (int i = tid; i < 2048; i += 256){
    int pix = i >> 6, c = i & 63;
    ynorm[(p0 + pix)*64 + c] = ls_s[c*33 + pix];
  }
  if (tid < 32){
    float s = 0.f, q = 0.f;
    #pragma unroll 8
    for (int c = 0; c < 64; ++c){
      float v = ls_s[c*33 + tid];
      s += v; q += v*v;
    }
    float m = s * (1.f/64.f);
    float va = q * (1.f/64.f) - m*m;
    mv_s[0][tid] = m;
    mv_s[1][tid] = rsqrtf(va + 1e-5f);
  }
  __syncthreads();
  for (int i = tid; i < 2048; i += 256){
    int c = i >> 5, pix = i & 31;
    float v = ls_s[c*33 + pix];
    ls_s[c*33 + pix] = (v - mv_s[0][pix]) * mv_s[1][pix] * ln_g[c] + ln_b[c];
  }
  __syncthreads();
  const int pix = tid & 31, eh = tid >> 5;
  float acc[32];
  #pragma unroll
  for (int j = 0; j < 32; ++j) acc[j] = 0.f;
  for (int c = 0; c < 64; ++c){
    float lnv = ls_s[c*33 + pix];
    const float4* w4 = (const float4*)(ws_s + c*256 + eh*32);
    #pragma unroll
    for (int j = 0; j < 8; ++j){
      float4 wq = w4[j];
      acc[j*4+0] = fmaf(lnv, wq.x, acc[j*4+0]);
      acc[j*4+1] = fmaf(lnv, wq.y, acc[j*4+1]);
      acc[j*4+2] = fmaf(lnv, wq.z, acc[j*4+2]);
      acc[j*4+3] = fmaf(lnv, wq.w, acc[j*4+3]);
    }
  }
  __syncthreads();
  float* szs = ws_s; // [pix][129]
  const int p = p0 + pix;
  if (eh < 4){
    const int e0 = eh*32;
    #pragma unroll
    for (int j = 0; j < 32; ++j)
      xa_pre[(e0+j)*L + p] = acc[j];
  } else {
    const int j0 = (eh-4)*32;
    #pragma unroll
    for (int j = 0; j < 32; ++j)
      szs[pix*129 + j0 + j] = siluf(acc[j]);
  }
  __syncthreads();
  for (int i = tid; i < 32*128; i += 256){
    int pix2 = i >> 7, j = i & 127;
    sz[(p0 + pix2)*128 + j] = szs[pix2*129 + j];
  }
}

// ---------------- K5: depthwise 3x3 (128ch) + bias + silu ------------------
__global__ __launch_bounds__(256) void k_dwc(
    const float* __restrict__ xa, const float* __restrict__ w, const float* __restrict__ b,
    float* __restrict__ u)
{
  int g = blockIdx.x * 256 + threadIdx.x;
  int p = g & (L-1);
  int d = g >> 14;
  int h = p >> 7, ww = p & 127;
  const float* xp = xa + d*L;
  const float* wp = w + d*9;
  float acc = b[d];
  #pragma unroll
  for (int ky = 0; ky < 3; ++ky){
    int hh = h + ky - 1;
    if ((unsigned)hh < 128u){
      #pragma unroll
      for (int kx = 0; kx < 3; ++kx){
        int wx = ww + kx - 1;
        if ((unsigned)wx < 128u)
          acc = fmaf(xp[hh*128 + wx], wp[ky*3+kx], acc);
      }
    }
  }
  u[d*L + p] = siluf(acc);
}

// ---------------- K5b: spatial transpose per channel: uT[d][w*128+h] -------
__global__ __launch_bounds__(256) void k_transp(
    const float* __restrict__ u, float* __restrict__ uT)
{
  __shared__ float t[32][33];
  int b = blockIdx.x;          // 128 ch * 16 tiles
  int d = b >> 4;
  int th = (b >> 2) & 3;
  int tw = b & 3;
  int lx = threadIdx.x & 31, ly = threadIdx.x >> 5;  // 32 x 8
  const float* src = u + d*L;
  #pragma unroll
  for (int i = 0; i < 4; ++i)
    t[ly + i*8][lx] = src[(th*32 + ly + i*8)*128 + tw*32 + lx];
  __syncthreads();
  float* dst = uT + d*L;
  #pragma unroll
  for (int i = 0; i < 4; ++i)
    dst[(tw*32 + ly + i*8)*128 + th*32 + lx] = t[lx][ly + i*8];
}

// ------- K6: x_proj (128->36 x2 dirs) + delta softplus, reg-u + scalar-w ---
// Block = 64 pixels, 256 thr: lane=pixel, grp=tid>>6 wave-uniform.
// Each thread: u row (128) in registers; 18 dots with s_load weights.
// PASS 0: k={0,2}, u_src=u (row-major); PASS 1: k={1,3}, u_src=uT.
template<int PASS>
__global__ __launch_bounds__(256) void k_projB(
    const float* __restrict__ u_src, const float* __restrict__ xw,
    const float* __restrict__ dtw, const float* __restrict__ dtb,
    float* __restrict__ delta_s, float* __restrict__ Bs, float* __restrict__ Cs,
    float* __restrict__ u_out)
{
  __shared__ float dts_s[64][2][4];
  const int tid = threadIdx.x;
  const int pix = tid & 63;
  const int grpu = __builtin_amdgcn_readfirstlane(tid >> 6);
  const int half = grpu & 1, kk = grpu >> 1;
  const int k = kk*2 + PASS;
  const int idx0 = blockIdx.x * 64;
  const int idx = idx0 + pix;

  float urg[128];
  #pragma unroll
  for (int d = 0; d < 128; ++d){
    urg[d] = u_src[d*L + idx];
    if ((d >> 5) == grpu) u_out[idx*128 + d] = urg[d];
  }

  const float* wbase = xw + (k*36 + half*18)*128;
  #pragma unroll
  for (int j = 0; j < 18; ++j){
    const float* wr = wbase + j*128;
    float s0 = 0.f, s1 = 0.f, s2 = 0.f, s3 = 0.f;
    #pragma unroll
    for (int q = 0; q < 32; ++q){
      s0 = fmaf(urg[q*4+0], wr[q*4+0], s0);
      s1 = fmaf(urg[q*4+1], wr[q*4+1], s1);
      s2 = fmaf(urg[q*4+2], wr[q*4+2], s2);
      s3 = fmaf(urg[q*4+3], wr[q*4+3], s3);
    }
    float acc = (s0+s1)+(s2+s3);
    if (half == 0){
      if (j < 4) dts_s[pix][kk][j] = acc;
      else       Bs[(k*L + idx)*16 + (j-4)] = acc;
    } else {
      if (j < 2) Bs[(k*L + idx)*16 + (14+j)] = acc;
      else       Cs[(k*L + idx)*16 + (j-2)] = acc;
    }
  }
  __syncthreads();

  const int d = tid & 127, ph = tid >> 7;
  #pragma unroll
  for (int pp = 0; pp < 32; ++pp){
    int px = pp*2 + ph;
    int ix = idx0 + px;
    #pragma unroll
    for (int q = 0; q < 2; ++q){
      int kq = q*2 + PASS;
      const float4 dw = *((const float4*)(dtw + (kq*128 + d)*4));
      float a = dtb[kq*128 + d];
      a = fmaf(dts_s[px][q][0], dw.x, a);
      a = fmaf(dts_s[px][q][1], dw.y, a);
      a = fmaf(dts_s[px][q][2], dw.z, a);
      a = fmaf(dts_s[px][q][3], dw.w, a);
      delta_s[(kq*L + ix)*128 + d] = softplusf(a);
    }
  }
}

// -------- K7: scan pass 1 — per-chunk (prod a, local h), n-split -----------
__global__ __launch_bounds__(256) void k_scan1(
    const float* __restrict__ delta_s, const float* __restrict__ u_row,
    const float* __restrict__ u_col, const float* __restrict__ Bs,
    const float* __restrict__ Alog, float* __restrict__ P, float* __restrict__ S)
{
  int blk = blockIdx.x;          // k*NCH + chunk
  int k = blk >> 7, ch = blk & (NCH-1);
  int tid = threadIdx.x;
  int d = tid & 127, nh = tid >> 7;
  const float* u_s = (k & 1) ? u_col : u_row;
  float A[8], Pv[8], Sv[8];
  #pragma unroll
  for (int j = 0; j < 8; ++j){
    A[j] = -__expf(Alog[(k*128 + d)*16 + nh*8 + j]);
    Pv[j] = 1.f; Sv[j] = 0.f;
  }
  int base = ch*CT;
  for (int t = 0; t < CT; ++t){
    int tl = base + t;
    int pos = (k < 2) ? tl : (L-1 - tl);
    float dl = delta_s[(k*L + pos)*128 + d];
    float du = dl * u_s[pos*128 + d];
    const float* Br = Bs + (k*L + pos)*16 + nh*8;
    #pragma unroll
    for (int j = 0; j < 8; ++j){
      float a = __expf(dl * A[j]);
      Sv[j] = fmaf(Sv[j], a, du * Br[j]);
      Pv[j] *= a;
    }
  }
  #pragma unroll
  for (int j = 0; j < 8; ++j){
    int o = (blk*16 + nh*8 + j)*128 + d;
    P[o] = Pv[j]; S[o] = Sv[j];
  }
}

// ---------------- K8: scan pass 2 — sequential over NCH chunks -------------
__global__ __launch_bounds__(256) void k_scan2(
    const float* __restrict__ P, const float* __restrict__ S, float* __restrict__ hst)
{
  int g = blockIdx.x * 256 + threadIdx.x;   // 8192 threads: k*2048 + n*128 + d
  int d = g & 127, n = (g >> 7) & 15, k = g >> 11;
  float h = 0.f;
  for (int c = 0; c < NCH; ++c){
    int o = (((k*NCH + c)*16) + n)*128 + d;
    hst[o] = h;
    h = fmaf(P[o], h, S[o]);
  }
}

// -------- K9: scan pass 3 — outputs, lane-pair n-split + shfl reduce -------
__global__ __launch_bounds__(256) void k_scan3(
    const float* __restrict__ delta_s, const float* __restrict__ u_row,
    const float* __restrict__ u_col, const float* __restrict__ Bs,
    const float* __restrict__ Cs, const float* __restrict__ Alog,
    const float* __restrict__ hst, float* __restrict__ ys)
{
  int blk = blockIdx.x;
  int k = blk >> 7, ch = blk & (NCH-1);
  int tid = threadIdx.x;
  int d = tid >> 1, nh = tid & 1;
  const float* u_s = (k & 1) ? u_col : u_row;
  float A[8], h[8];
  #pragma unroll
  for (int j = 0; j < 8; ++j){
    A[j] = -__expf(Alog[(k*128 + d)*16 + nh*8 + j]);
    h[j] = hst[(blk*16 + nh*8 + j)*128 + d];
  }
  int base = ch*CT;
  for (int t = 0; t < CT; ++t){
    int tl = base + t;
    int pos = (k < 2) ? tl : (L-1 - tl);
    float dl = delta_s[(k*L + pos)*128 + d];
    float du = dl * u_s[pos*128 + d];
    const float* Br = Bs + (k*L + pos)*16 + nh*8;
    const float* Cr = Cs + (k*L + pos)*16 + nh*8;
    float y = 0.f;
    #pragma unroll
    for (int j = 0; j < 8; ++j){
      float a = __expf(dl * A[j]);
      h[j] = fmaf(h[j], a, du * Br[j]);
      y = fmaf(h[j], Cr[j], y);
    }
    y += __shfl_xor(y, 1);
    if (nh == 0) ys[(k*L + pos)*128 + d] = y;
  }
}

// ------- K10: combine 4 dirs + u*sumD + LN(128) + gate + out_proj + add ----
__global__ __launch_bounds__(128) void k_combine(
    const float* __restrict__ ys, const float* __restrict__ u_row,
    const float* __restrict__ Ds, const float* __restrict__ on_g,
    const float* __restrict__ on_b, const float* __restrict__ sz,
    const float* __restrict__ out_w, const float* __restrict__ ynorm,
    float* __restrict__ yp2)
{
  __shared__ float gs[128];
  __shared__ float rbuf[2][2];
  int p = blockIdx.x;
  int d = threadIdx.x;
  int h = p >> 7, w = p & 127;
  int pT = w*128 + h;
  float y = ys[(0*L + p )*128 + d] + ys[(2*L + p )*128 + d]
          + ys[(1*L + pT)*128 + d] + ys[(3*L + pT)*128 + d];
  float sumD = Ds[d] + Ds[128 + d] + Ds[256 + d] + Ds[384 + d];
  y = fmaf(u_row[p*128 + d], sumD, y);
  float s = wave_sum(y);
  float sq = wave_sum(y*y);
  if ((d & 63) == 0){ rbuf[d>>6][0] = s; rbuf[d>>6][1] = sq; }
  __syncthreads();
  float ts = rbuf[0][0] + rbuf[1][0];
  float tq = rbuf[0][1] + rbuf[1][1];
  float m = ts * (1.f/128.f);
  float va = tq * (1.f/128.f) - m*m;
  float yn = (y - m) * rsqrtf(va + 1e-5f) * on_g[d] + on_b[d];
  gs[d] = yn * sz[p*128 + d];
  __syncthreads();
  if (d < 64){
    const float4* wr = (const float4*)(out_w + d*128);
    const float4* gr = (const float4*)gs;
    float acc = 0.f;
    #pragma unroll
    for (int i = 0; i < 32; ++i){
      float4 a = gr[i], bw = wr[i];
      acc = fmaf(a.x, bw.x, acc); acc = fmaf(a.y, bw.y, acc);
      acc = fmaf(a.z, bw.z, acc); acc = fmaf(a.w, bw.w, acc);
    }
    yp2[p*64 + d] = ynorm[p*64 + d] + acc;
  }
}

// ---------------- K11: depthwise 3x3 (64ch, NHWC) + bias -------------------
__global__ __launch_bounds__(256) void k_dw2a(
    const float* __restrict__ yp2, const float* __restrict__ w,
    const float* __restrict__ b, float* __restrict__ t2)
{
  int g = blockIdx.x * 256 + threadIdx.x;   // 64 * 16384
  int c = g & 63;
  int p = g >> 6;
  int h = p >> 7, ww = p & 127;
  const float* wp = w + c*9;
  float acc = b[c];
  #pragma unroll
  for (int ky = 0; ky < 3; ++ky){
    int hh = h + ky - 1;
    if ((unsigned)hh < 128u){
      #pragma unroll
      for (int kx = 0; kx < 3; ++kx){
        int wx = ww + kx - 1;
        if ((unsigned)wx < 128u)
          acc = fmaf(yp2[(hh*128 + wx)*64 + c], wp[ky*3+kx], acc);
      }
    }
  }
  t2[p*64 + c] = acc;
}

// ---------------- K12: 1x1 64->64 + bias + relu + residual -----------------
__global__ __launch_bounds__(256) void k_dw2b(
    const float* __restrict__ t2, const float* __restrict__ w,
    const float* __restrict__ b, const float* __restrict__ x,
    float* __restrict__ out)
{
  __shared__ float s[16][65];
  int p0 = blockIdx.x * 16;
  for (int i = threadIdx.x; i < 1024; i += 256){
    int pix = i >> 6, c = i & 63;
    s[pix][c] = t2[(p0 + pix)*64 + c];
  }
  __syncthreads();
  int dp = threadIdx.x & 15, cg = threadIdx.x >> 4;
  #pragma unroll
  for (int cc = 0; cc < 4; ++cc){
    int c = cg + cc*16;
    float acc = b[c];
    const float* wp = w + c*64;
    #pragma unroll 8
    for (int i = 0; i < 64; ++i) acc = fmaf(s[dp][i], wp[i], acc);
    acc = fmaxf(acc, 0.f);
    int p = p0 + dp;
    out[c*L + p] = acc + x[c*L + p];
  }
}

extern "C" void kernel_launch(void* const* d_in, const int* in_sizes, int n_in,
                              void* d_out, int out_size, void* d_ws, size_t ws_size,
                              hipStream_t stream)
{
  const float* x       = (const float*)d_in[0];
  const float* conv1_w = (const float*)d_in[1];
  const float* conv1_b = (const float*)d_in[2];
  const float* conv2_w = (const float*)d_in[3];
  const float* conv2_b = (const float*)d_in[4];
  const float* dw1a_w  = (const float*)d_in[5];
  const float* dw1a_b  = (const float*)d_in[6];
  const float* dw1b_w  = (const float*)d_in[7];
  const float* dw1b_b  = (const float*)d_in[8];
  const float* dw2a_w  = (const float*)d_in[9];
  const float* dw2a_b  = (const float*)d_in[10];
  const float* dw2b_w  = (const float*)d_in[11];
  const float* dw2b_b  = (const float*)d_in[12];
  const float* ln_g    = (const float*)d_in[13];
  const float* ln_b    = (const float*)d_in[14];
  const float* ipw     = (const float*)d_in[15];
  const float* cdw_w   = (const float*)d_in[16];
  const float* cdw_b   = (const float*)d_in[17];
  const float* xw      = (const float*)d_in[18];
  const float* dtw     = (const float*)d_in[19];
  const float* dtb     = (const float*)d_in[20];
  const float* Alog    = (const float*)d_in[21];
  const float* DsArr   = (const float*)d_in[22];
  const float* on_g    = (const float*)d_in[23];
  const float* on_b    = (const float*)d_in[24];
  const float* out_w   = (const float*)d_in[25];
  float* out = (float*)d_out;

  char* ws = (char*)d_ws;
  const size_t MB = 1048576ull;
  float* y1      = (float*)(ws + 0*MB);    // 8MB   convred -> K2 (dead after dw1a)
  float* uT      = (float*)(ws + 0*MB);    // 8MB   transp -> projB<1> (reuses y1)
  float* t1      = (float*)(ws + 8*MB);    // 8MB   K2 -> K3
  float* y2      = (float*)(ws + 16*MB);   // 4MB   K3 -> K4
  float* xpad    = (float*)(ws + 20*MB);   // 4.6MB pad -> conv (dead after; xa_pre reuses)
  float* xa_pre  = (float*)(ws + 20*MB);   // 8MB   K4 -> K5
  float* wT1     = (float*)(ws + 28*MB);           // 144KB  prep -> conv
  float* wT2     = (float*)(ws + 28*MB + 524288);  // 400KB  prep -> conv
  float* ipwT    = (float*)(ws + 29*MB);           // 64KB   prep -> K4
  float* red     = (float*)(ws + 30*MB);           // 8B     K3 -> K4
  float* part1   = (float*)(ws + 32*MB);   // 16MB  convD3 -> convred (delta_s reuses)
  float* part2   = (float*)(ws + 48*MB);   // 16MB  convD5 -> convred
  float* ysb     = (float*)(ws + 0*MB);    // 32MB  K9 -> K10 (reuses 0-32, all dead)
  float* delta_s = (float*)(ws + 32*MB);   // 32MB  K6 -> K7/K9
  float* ynorm   = (float*)(ws + 64*MB);   // 4MB   K4 -> K10
  float* sz      = (float*)(ws + 68*MB);   // 8MB   K4 -> K10
  float* u       = (float*)(ws + 76*MB);   // 8MB   K5 -> K6
  float* u_row   = (float*)(ws + 84*MB);   // 8MB   K6 -> K7/K9/K10
  float* u_col   = (float*)(ws + 92*MB);   // 8MB   K6 -> K7/K9
  float* Bsb     = (float*)(ws + 100*MB);  // 4MB   K6 -> K7/K9
  float* Csb     = (float*)(ws + 104*MB);  // 4MB   K6 -> K9
  float* Pb      = (float*)(ws + 108*MB);  // 4MB   K7 -> K8   (NCH=128)
  float* Sb      = (float*)(ws + 112*MB);  // 4MB   K7 -> K8
  float* hst     = (float*)(ws + 116*MB);  // 4MB   K8 -> K9
  float* yp2     = (float*)(ws + 108*MB);  // 4MB   K10 -> K11 (reuses Pb, dead)
  float* t2      = (float*)(ws + 112*MB);  // 4MB   K11 -> K12 (reuses Sb, dead)

  hipMemsetAsync(red, 0, 2*sizeof(float), stream);

  k_prep    <<<608, 256, 0, stream>>>(conv1_w, conv2_w, ipw, wT1, wT2, ipwT);
  k_pad     <<<4488, 256, 0, stream>>>(x, xpad);
  k_convD<3><<<2048, 256, 0, stream>>>(xpad, wT1, part1);
  k_convD<5><<<2048, 256, 0, stream>>>(xpad, wT2, part2);
  k_convred <<<8192, 256, 0, stream>>>(part1, part2, conv1_b, conv2_b, y1);
  k_dw1a  <<<8192, 256, 0, stream>>>(y1, dw1a_w, dw1a_b, t1);
  k_dw1b  <<<1024, 256, 0, stream>>>(t1, dw1b_w, dw1b_b, y2, red);
  k_norm_inproj<<<512, 256, 0, stream>>>(y2, red, ln_g, ln_b, ipwT, ynorm, xa_pre, sz);
  k_dwc   <<<8192, 256, 0, stream>>>(xa_pre, cdw_w, cdw_b, u);
  k_transp<<<2048, 256, 0, stream>>>(u, uT);
  k_projB<0><<<256, 256, 0, stream>>>(u,  xw, dtw, dtb, delta_s, Bsb, Csb, u_row);
  k_projB<1><<<256, 256, 0, stream>>>(uT, xw, dtw, dtb, delta_s, Bsb, Csb, u_col);
  k_scan1 <<<4*NCH, 256, 0, stream>>>(delta_s, u_row, u_col, Bsb, Alog, Pb, Sb);
  k_scan2 <<<32, 256, 0, stream>>>(Pb, Sb, hst);
  k_scan3 <<<4*NCH, 256, 0, stream>>>(delta_s, u_row, u_col, Bsb, Csb, Alog, hst, ysb);
  k_combine<<<16384, 128, 0, stream>>>(ysb, u_row, DsArr, on_g, on_b, sz, out_w, ynorm, yp2);
  k_dw2a  <<<4096, 256, 0, stream>>>(yp2, dw2a_w, dw2a_b, t2);
  k_dw2b  <<<1024, 256, 0, stream>>>(t2, dw2b_w, dw2b_b, x, out);
}